// Round 9
// baseline (141.835 us; speedup 1.0000x reference)
//
#include <hip/hip_runtime.h>
#include <math.h>

#define BB 4
#define SS 256
#define DD 768
#define DEPC 100
#define HH 12

#define GLDS(gp, lp)                                                        \
    __builtin_amdgcn_global_load_lds(                                       \
        (const __attribute__((address_space(1))) void*)(gp),                \
        (__attribute__((address_space(3))) void*)(lp), 16, 0, 0)

// ---------- K1: u_t[h][p] = sum_d W_e[p][h*64+d] * w_rel[d]  (transposed) ----------
__global__ __launch_bounds__(256) void k_u(const float* __restrict__ W_e,
                                           const float* __restrict__ w_rel,
                                           float* __restrict__ u_t) {
    int e = blockIdx.x * 256 + threadIdx.x;
    if (e >= DEPC * HH) return;
    int p = e / HH, h = e % HH;
    const float4* we = (const float4*)(W_e + p * DD + h * 64);
    const float4* wr = (const float4*)w_rel;
    float acc = 0.f;
#pragma unroll
    for (int c = 0; c < 16; ++c) {
        float4 a = we[c], b = wr[c];
        acc += a.x * b.x + a.y * b.y + a.z * b.z + a.w * b.w;
    }
    u_t[h * DEPC + p] = acc;
}

// ---------- K2: V = token @ W_v.  32x32 tiles, grid 768 (3 blocks/CU) ----------
#define TM 32
#define TN 32
#define TKK 16
__global__ __launch_bounds__(256) void k_v(const float* __restrict__ A,
                                           const float* __restrict__ Bm,
                                           float* __restrict__ C) {
    __shared__ float As[TKK][TM + 1];  // [k][row]
    __shared__ float Bs[TKK][TN];      // [k][col]
    int t = threadIdx.x;
    int r = t >> 3, c4 = t & 7;        // output: row r, cols 4*c4..4*c4+3
    int r0 = blockIdx.x * TM, c0 = blockIdx.y * TN;
    float acc[4] = {};
    // staging roles: threads 0-127 -> A (one float4), 128-255 -> B (one float4)
    int sa = t & 127, isB = t >> 7;
    int ar = sa >> 2, aq = sa & 3;     // A: row, k-quad
    int bk = sa >> 3, bq = sa & 7;     // B: k, col-quad

    // stage k0 = 0
    if (!isB) {
        float4 v = *(const float4*)&A[(r0 + ar) * DD + 4 * aq];
#pragma unroll
        for (int m = 0; m < 4; ++m) As[4 * aq + m][ar] = ((const float*)&v)[m];
    } else {
        *(float4*)&Bs[bk][4 * bq] = *(const float4*)&Bm[bk * DD + c0 + 4 * bq];
    }
    __syncthreads();

    for (int k0 = 0; k0 < DD; k0 += TKK) {
        float4 nx = {0, 0, 0, 0};
        if (k0 + TKK < DD) {
            int kn = k0 + TKK;
            nx = isB ? *(const float4*)&Bm[(kn + bk) * DD + c0 + 4 * bq]
                     : *(const float4*)&A[(r0 + ar) * DD + kn + 4 * aq];
        }
#pragma unroll
        for (int kk = 0; kk < TKK; ++kk) {
            float a = As[kk][r];
            float4 b = *(const float4*)&Bs[kk][4 * c4];
            acc[0] += a * b.x; acc[1] += a * b.y;
            acc[2] += a * b.z; acc[3] += a * b.w;
        }
        __syncthreads();
        if (k0 + TKK < DD) {
            if (!isB) {
#pragma unroll
                for (int m = 0; m < 4; ++m) As[4 * aq + m][ar] = ((const float*)&nx)[m];
            } else {
                *(float4*)&Bs[bk][4 * bq] = nx;
            }
        }
        __syncthreads();
    }
    *(float4*)&C[(size_t)(r0 + r) * DD + c0 + 4 * c4] =
        make_float4(acc[0], acc[1], acc[2], acc[3]);
}

// ---------- K3: scores — one-shot 64-row blocks, u in LDS (wave-broadcast) ----------
// grid 4096, LDS 30.4 KB -> 5 blocks/CU. All loop loads are ds_read (single DS
// queue, in-order) -> counted lgkmcnt, no SMEM-mixing drains.
__global__ __launch_bounds__(256) void k_sc(const float* __restrict__ edge,
                                            const int* __restrict__ mask,
                                            const float* __restrict__ ut,
                                            float* __restrict__ scores) {
    __shared__ float buf[64 * DEPC];   // 25.6 KB
    __shared__ float u_l[HH * DEPC];   // 4.8 KB, [h][p]
    int t = threadIdx.x;
    int jc = blockIdx.x & 3;
    int i  = blockIdx.x >> 2;
    int b  = blockIdx.y;
    int lane = t & 63, w = t >> 6;

    const float* src = edge + (size_t)((b * SS + i) * SS + jc * 64) * DEPC;
    for (int call = w; call < 25; call += 4)
        GLDS(src + call * 256 + lane * 4, &buf[call * 256]);

    {   // stage u (1200 floats = 300 float4)
        const float4* ug4 = (const float4*)ut;
        float4* ul4 = (float4*)u_l;
        if (t < 256) ul4[t] = ug4[t];
        if (t < 44)  ul4[256 + t] = ug4[256 + t];
    }
    int mk = mask[(size_t)(b * SS + i) * SS + jc * 64 + lane];
    __syncthreads();

    int hbase = __builtin_amdgcn_readfirstlane(w * 3);
    const float4* U0 = (const float4*)(u_l + (hbase + 0) * DEPC);  // 400B-aligned
    const float4* U1 = (const float4*)(u_l + (hbase + 1) * DEPC);
    const float4* U2 = (const float4*)(u_l + (hbase + 2) * DEPC);
    const float4* row4 = (const float4*)(buf + lane * DEPC);

    float4 A0 = {0, 0, 0, 0}, A1 = {0, 0, 0, 0}, A2 = {0, 0, 0, 0};
#pragma unroll
    for (int ph = 0; ph < 5; ++ph) {
        float4 e4[5], u0[5], u1[5], u2[5];
#pragma unroll
        for (int q = 0; q < 5; ++q) {
            int p4 = ph * 5 + q;
            e4[q] = row4[p4];
            u0[q] = U0[p4];   // wave-uniform addr -> LDS broadcast
            u1[q] = U1[p4];
            u2[q] = U2[p4];
        }
#pragma unroll
        for (int q = 0; q < 5; ++q) {
            A0.x += e4[q].x * u0[q].x; A0.y += e4[q].y * u0[q].y;
            A0.z += e4[q].z * u0[q].z; A0.w += e4[q].w * u0[q].w;
            A1.x += e4[q].x * u1[q].x; A1.y += e4[q].y * u1[q].y;
            A1.z += e4[q].z * u1[q].z; A1.w += e4[q].w * u1[q].w;
            A2.x += e4[q].x * u2[q].x; A2.y += e4[q].y * u2[q].y;
            A2.z += e4[q].z * u2[q].z; A2.w += e4[q].w * u2[q].w;
        }
    }
    float a0 = (A0.x + A0.y) + (A0.z + A0.w);
    float a1 = (A1.x + A1.y) + (A1.z + A1.w);
    float a2 = (A2.x + A2.y) + (A2.z + A2.w);

    int j = jc * 64 + lane;
    size_t sb = (((size_t)b * HH + hbase) * SS + i) * SS + j;
    scores[sb]                       = mk ? fmaxf(a0, 0.f) : -1e6f;
    scores[sb + (size_t)SS * SS]     = mk ? fmaxf(a1, 0.f) : -1e6f;
    scores[sb + 2 * (size_t)SS * SS] = mk ? fmaxf(a2, 0.f) : -1e6f;
}

// ---------- K4: softmax + ctx, 512 threads (j-range split across halves) ----------
#define GG 4
__global__ __launch_bounds__(512) void k_ctx(const float* __restrict__ scores,
                                             const float* __restrict__ V,
                                             const float* __restrict__ token,
                                             float* __restrict__ out) {
    __shared__ float sc[GG][HH][SS];  // 48 KB
    __shared__ float red[GG][DD];     // 12.3 KB partials
    int t = threadIdx.x, b = blockIdx.y, i0 = blockIdx.x * GG;
    for (int idx = t; idx < GG * HH * (SS / 4); idx += 512) {
        int jc = idx & 63, rr = idx >> 6;
        int g = rr / HH, h = rr % HH;
        float4 v = *(const float4*)(scores + (((size_t)b * HH + h) * SS + (i0 + g)) * SS + 4 * jc);
        *(float4*)&sc[g][h][4 * jc] = v;
    }
    __syncthreads();
    int lane = t & 63, w = t >> 6;  // 8 waves
    for (int rr = w; rr < GG * HH; rr += 8) {
        int g = rr / HH, h = rr % HH;
        float x0 = sc[g][h][lane],       x1 = sc[g][h][lane + 64];
        float x2 = sc[g][h][lane + 128], x3 = sc[g][h][lane + 192];
        float m = fmaxf(fmaxf(x0, x1), fmaxf(x2, x3));
#pragma unroll
        for (int o = 32; o > 0; o >>= 1) m = fmaxf(m, __shfl_xor(m, o, 64));
        x0 = __expf(x0 - m); x1 = __expf(x1 - m);
        x2 = __expf(x2 - m); x3 = __expf(x3 - m);
        float s = x0 + x1 + x2 + x3;
#pragma unroll
        for (int o = 32; o > 0; o >>= 1) s += __shfl_xor(s, o, 64);
        float inv = 1.0f / s;
        sc[g][h][lane] = x0 * inv;       sc[g][h][lane + 64] = x1 * inv;
        sc[g][h][lane + 128] = x2 * inv; sc[g][h][lane + 192] = x3 * inv;
    }
    __syncthreads();
    int half = t >> 8, tt = t & 255;
    float acc[3][GG] = {};
    for (int j0 = half * 128; j0 < half * 128 + 128; j0 += 4) {
#pragma unroll
        for (int a = 0; a < 3; ++a) {
            int hd = tt + 256 * a;
            int h = hd >> 6;
            float v0 = V[(size_t)(b * SS + j0) * DD + hd];
            float v1 = V[(size_t)(b * SS + j0 + 1) * DD + hd];
            float v2 = V[(size_t)(b * SS + j0 + 2) * DD + hd];
            float v3 = V[(size_t)(b * SS + j0 + 3) * DD + hd];
#pragma unroll
            for (int g = 0; g < GG; ++g) {
                float4 p = *(const float4*)&sc[g][h][j0];
                acc[a][g] += p.x * v0 + p.y * v1 + p.z * v2 + p.w * v3;
            }
        }
    }
    if (half == 1) {
#pragma unroll
        for (int a = 0; a < 3; ++a)
#pragma unroll
            for (int g = 0; g < GG; ++g) red[g][tt + 256 * a] = acc[a][g];
    }
    __syncthreads();
    if (half == 0) {
#pragma unroll
        for (int a = 0; a < 3; ++a) {
            int hd = tt + 256 * a;
#pragma unroll
            for (int g = 0; g < GG; ++g) {
                size_t o = (size_t)(b * SS + i0 + g) * DD + hd;
                out[o] = fmaxf(token[o] + acc[a][g] + red[g][hd], 0.f);
            }
        }
    }
}

extern "C" void kernel_launch(void* const* d_in, const int* in_sizes, int n_in,
                              void* d_out, int out_size, void* d_ws, size_t ws_size,
                              hipStream_t stream) {
    const float* token = (const float*)d_in[0];
    const float* edge  = (const float*)d_in[1];
    const int*   mask  = (const int*)d_in[2];
    const float* W_v   = (const float*)d_in[3];
    const float* W_e   = (const float*)d_in[4];
    const float* w_rel = (const float*)d_in[5];
    float* out = (float*)d_out;

    char* ws = (char*)d_ws;
    float* u_t    = (float*)(ws);                                   // 4.8 KB
    float* V      = (float*)(ws + 8192);                            // 3.15 MB
    float* scores = (float*)(ws + 8192 + (size_t)BB * SS * DD * 4); // 12.6 MB

    hipLaunchKernelGGL(k_u,   dim3((DEPC * HH + 255) / 256), dim3(256), 0, stream, W_e, w_rel, u_t);
    hipLaunchKernelGGL(k_v,   dim3((BB * SS) / TM, DD / TN), dim3(256), 0, stream, token, W_v, V);
    hipLaunchKernelGGL(k_sc,  dim3(SS * 4, BB),              dim3(256), 0, stream, edge, mask, u_t, scores);
    hipLaunchKernelGGL(k_ctx, dim3(SS / GG, BB),             dim3(512), 0, stream, scores, V, token, out);
}

// Round 10
// 136.981 us; speedup vs baseline: 1.0354x; 1.0354x over previous
//
#include <hip/hip_runtime.h>
#include <math.h>

#define BB 4
#define SS 256
#define DD 768
#define DEPC 100
#define HH 12

#define GLDS(gp, lp)                                                        \
    __builtin_amdgcn_global_load_lds(                                       \
        (const __attribute__((address_space(1))) void*)(gp),                \
        (__attribute__((address_space(3))) void*)(lp), 16, 0, 0)

// ---------- K1: u_t[h][p] = sum_d W_e[p][h*64+d] * w_rel[d]  (transposed) ----------
__global__ __launch_bounds__(256) void k_u(const float* __restrict__ W_e,
                                           const float* __restrict__ w_rel,
                                           float* __restrict__ u_t) {
    int e = blockIdx.x * 256 + threadIdx.x;
    if (e >= DEPC * HH) return;
    int p = e / HH, h = e % HH;
    const float4* we = (const float4*)(W_e + p * DD + h * 64);
    const float4* wr = (const float4*)w_rel;
    float acc = 0.f;
#pragma unroll
    for (int c = 0; c < 16; ++c) {
        float4 a = we[c], b = wr[c];
        acc += a.x * b.x + a.y * b.y + a.z * b.z + a.w * b.w;
    }
    u_t[h * DEPC + p] = acc;
}

// ---------- K2: V = token @ W_v.  32x32 tiles, grid 768 (3 blocks/CU) ----------
#define TM 32
#define TN 32
#define TKK 16
__global__ __launch_bounds__(256) void k_v(const float* __restrict__ A,
                                           const float* __restrict__ Bm,
                                           float* __restrict__ C) {
    __shared__ float As[TKK][TM + 1];  // [k][row]
    __shared__ float Bs[TKK][TN];      // [k][col]
    int t = threadIdx.x;
    int r = t >> 3, c4 = t & 7;        // output: row r, cols 4*c4..4*c4+3
    int r0 = blockIdx.x * TM, c0 = blockIdx.y * TN;
    float acc[4] = {};
    int sa = t & 127, isB = t >> 7;
    int ar = sa >> 2, aq = sa & 3;     // A: row, k-quad
    int bk = sa >> 3, bq = sa & 7;     // B: k, col-quad

    if (!isB) {
        float4 v = *(const float4*)&A[(r0 + ar) * DD + 4 * aq];
#pragma unroll
        for (int m = 0; m < 4; ++m) As[4 * aq + m][ar] = ((const float*)&v)[m];
    } else {
        *(float4*)&Bs[bk][4 * bq] = *(const float4*)&Bm[bk * DD + c0 + 4 * bq];
    }
    __syncthreads();

    for (int k0 = 0; k0 < DD; k0 += TKK) {
        float4 nx = {0, 0, 0, 0};
        if (k0 + TKK < DD) {
            int kn = k0 + TKK;
            nx = isB ? *(const float4*)&Bm[(kn + bk) * DD + c0 + 4 * bq]
                     : *(const float4*)&A[(r0 + ar) * DD + kn + 4 * aq];
        }
#pragma unroll
        for (int kk = 0; kk < TKK; ++kk) {
            float a = As[kk][r];
            float4 b = *(const float4*)&Bs[kk][4 * c4];
            acc[0] += a * b.x; acc[1] += a * b.y;
            acc[2] += a * b.z; acc[3] += a * b.w;
        }
        __syncthreads();
        if (k0 + TKK < DD) {
            if (!isB) {
#pragma unroll
                for (int m = 0; m < 4; ++m) As[4 * aq + m][ar] = ((const float*)&nx)[m];
            } else {
                *(float4*)&Bs[bk][4 * bq] = nx;
            }
        }
        __syncthreads();
    }
    *(float4*)&C[(size_t)(r0 + r) * DD + c0 + 4 * c4] =
        make_float4(acc[0], acc[1], acc[2], acc[3]);
}

// ---------- K3: scores — one-shot 64-row blocks; u via divergent global loads ----------
// e-reads: ds_read (counted lgkmcnt, DS-only queue). u-reads: global_load_dwordx4
// (vmcnt queue, L1-broadcast: all lanes same addr). No s_load/ds lgkmcnt mixing.
__global__ __launch_bounds__(256) void k_sc(const float* __restrict__ edge,
                                            const int* __restrict__ mask,
                                            const float* __restrict__ ut,
                                            float* __restrict__ scores) {
    __shared__ float buf[64 * DEPC];   // 25.6 KB
    int t = threadIdx.x;
    int jc = blockIdx.x & 3;
    int i  = blockIdx.x >> 2;
    int b  = blockIdx.y;
    int lane = t & 63, w = t >> 6;

    const float* src = edge + (size_t)((b * SS + i) * SS + jc * 64) * DEPC;
    for (int call = w; call < 25; call += 4)
        GLDS(src + call * 256 + lane * 4, &buf[call * 256]);

    int mk = mask[(size_t)(b * SS + i) * SS + jc * 64 + lane];

    // deliberately NOT readfirstlane: t>>6 is divergent to the compiler ->
    // vector loads; hardware broadcasts the (per-wave-uniform) cacheline.
    int hbase = (t >> 6) * 3;
    const float4* U0 = (const float4*)(ut + (hbase + 0) * DEPC);
    const float4* U1 = (const float4*)(ut + (hbase + 1) * DEPC);
    const float4* U2 = (const float4*)(ut + (hbase + 2) * DEPC);
    __syncthreads();

    const float4* row4 = (const float4*)(buf + lane * DEPC);
    float4 A0 = {0, 0, 0, 0}, A1 = {0, 0, 0, 0}, A2 = {0, 0, 0, 0};
#pragma unroll
    for (int ph = 0; ph < 5; ++ph) {
        float4 e4[5], u0[5], u1[5], u2[5];
#pragma unroll
        for (int q = 0; q < 5; ++q) {
            int p4 = ph * 5 + q;
            e4[q] = row4[p4];
            u0[q] = U0[p4];
            u1[q] = U1[p4];
            u2[q] = U2[p4];
        }
#pragma unroll
        for (int q = 0; q < 5; ++q) {
            A0.x += e4[q].x * u0[q].x; A0.y += e4[q].y * u0[q].y;
            A0.z += e4[q].z * u0[q].z; A0.w += e4[q].w * u0[q].w;
            A1.x += e4[q].x * u1[q].x; A1.y += e4[q].y * u1[q].y;
            A1.z += e4[q].z * u1[q].z; A1.w += e4[q].w * u1[q].w;
            A2.x += e4[q].x * u2[q].x; A2.y += e4[q].y * u2[q].y;
            A2.z += e4[q].z * u2[q].z; A2.w += e4[q].w * u2[q].w;
        }
        __builtin_amdgcn_sched_barrier(0);  // keep u-loads phase-local (no hoist->spill)
    }
    float a0 = (A0.x + A0.y) + (A0.z + A0.w);
    float a1 = (A1.x + A1.y) + (A1.z + A1.w);
    float a2 = (A2.x + A2.y) + (A2.z + A2.w);

    int j = jc * 64 + lane;
    size_t sb = (((size_t)b * HH + hbase) * SS + i) * SS + j;
    scores[sb]                       = mk ? fmaxf(a0, 0.f) : -1e6f;
    scores[sb + (size_t)SS * SS]     = mk ? fmaxf(a1, 0.f) : -1e6f;
    scores[sb + 2 * (size_t)SS * SS] = mk ? fmaxf(a2, 0.f) : -1e6f;
}

// ---------- K4: softmax + ctx, 512 threads (j-range split across halves) ----------
#define GG 4
__global__ __launch_bounds__(512) void k_ctx(const float* __restrict__ scores,
                                             const float* __restrict__ V,
                                             const float* __restrict__ token,
                                             float* __restrict__ out) {
    __shared__ float sc[GG][HH][SS];  // 48 KB
    __shared__ float red[GG][DD];     // 12.3 KB partials
    int t = threadIdx.x, b = blockIdx.y, i0 = blockIdx.x * GG;
    for (int idx = t; idx < GG * HH * (SS / 4); idx += 512) {
        int jc = idx & 63, rr = idx >> 6;
        int g = rr / HH, h = rr % HH;
        float4 v = *(const float4*)(scores + (((size_t)b * HH + h) * SS + (i0 + g)) * SS + 4 * jc);
        *(float4*)&sc[g][h][4 * jc] = v;
    }
    __syncthreads();
    int lane = t & 63, w = t >> 6;  // 8 waves
    for (int rr = w; rr < GG * HH; rr += 8) {
        int g = rr / HH, h = rr % HH;
        float x0 = sc[g][h][lane],       x1 = sc[g][h][lane + 64];
        float x2 = sc[g][h][lane + 128], x3 = sc[g][h][lane + 192];
        float m = fmaxf(fmaxf(x0, x1), fmaxf(x2, x3));
#pragma unroll
        for (int o = 32; o > 0; o >>= 1) m = fmaxf(m, __shfl_xor(m, o, 64));
        x0 = __expf(x0 - m); x1 = __expf(x1 - m);
        x2 = __expf(x2 - m); x3 = __expf(x3 - m);
        float s = x0 + x1 + x2 + x3;
#pragma unroll
        for (int o = 32; o > 0; o >>= 1) s += __shfl_xor(s, o, 64);
        float inv = 1.0f / s;
        sc[g][h][lane] = x0 * inv;       sc[g][h][lane + 64] = x1 * inv;
        sc[g][h][lane + 128] = x2 * inv; sc[g][h][lane + 192] = x3 * inv;
    }
    __syncthreads();
    int half = t >> 8, tt = t & 255;
    float acc[3][GG] = {};
    for (int j0 = half * 128; j0 < half * 128 + 128; j0 += 4) {
#pragma unroll
        for (int a = 0; a < 3; ++a) {
            int hd = tt + 256 * a;
            int h = hd >> 6;
            float v0 = V[(size_t)(b * SS + j0) * DD + hd];
            float v1 = V[(size_t)(b * SS + j0 + 1) * DD + hd];
            float v2 = V[(size_t)(b * SS + j0 + 2) * DD + hd];
            float v3 = V[(size_t)(b * SS + j0 + 3) * DD + hd];
#pragma unroll
            for (int g = 0; g < GG; ++g) {
                float4 p = *(const float4*)&sc[g][h][j0];
                acc[a][g] += p.x * v0 + p.y * v1 + p.z * v2 + p.w * v3;
            }
        }
    }
    if (half == 1) {
#pragma unroll
        for (int a = 0; a < 3; ++a)
#pragma unroll
            for (int g = 0; g < GG; ++g) red[g][tt + 256 * a] = acc[a][g];
    }
    __syncthreads();
    if (half == 0) {
#pragma unroll
        for (int a = 0; a < 3; ++a) {
            int hd = tt + 256 * a;
#pragma unroll
            for (int g = 0; g < GG; ++g) {
                size_t o = (size_t)(b * SS + i0 + g) * DD + hd;
                out[o] = fmaxf(token[o] + acc[a][g] + red[g][hd], 0.f);
            }
        }
    }
}

extern "C" void kernel_launch(void* const* d_in, const int* in_sizes, int n_in,
                              void* d_out, int out_size, void* d_ws, size_t ws_size,
                              hipStream_t stream) {
    const float* token = (const float*)d_in[0];
    const float* edge  = (const float*)d_in[1];
    const int*   mask  = (const int*)d_in[2];
    const float* W_v   = (const float*)d_in[3];
    const float* W_e   = (const float*)d_in[4];
    const float* w_rel = (const float*)d_in[5];
    float* out = (float*)d_out;

    char* ws = (char*)d_ws;
    float* u_t    = (float*)(ws);                                   // 4.8 KB
    float* V      = (float*)(ws + 8192);                            // 3.15 MB
    float* scores = (float*)(ws + 8192 + (size_t)BB * SS * DD * 4); // 12.6 MB

    hipLaunchKernelGGL(k_u,   dim3((DEPC * HH + 255) / 256), dim3(256), 0, stream, W_e, w_rel, u_t);
    hipLaunchKernelGGL(k_v,   dim3((BB * SS) / TM, DD / TN), dim3(256), 0, stream, token, W_v, V);
    hipLaunchKernelGGL(k_sc,  dim3(SS * 4, BB),              dim3(256), 0, stream, edge, mask, u_t, scores);
    hipLaunchKernelGGL(k_ctx, dim3(SS / GG, BB),             dim3(512), 0, stream, scores, V, token, out);
}

// Round 11
// 107.045 us; speedup vs baseline: 1.3250x; 1.2797x over previous
//
#include <hip/hip_runtime.h>
#include <math.h>

#define BB 4
#define SS 256
#define DD 768
#define DEPC 100
#define HH 12

#define GLDS(gp, lp)                                                        \
    __builtin_amdgcn_global_load_lds(                                       \
        (const __attribute__((address_space(1))) void*)(gp),                \
        (__attribute__((address_space(3))) void*)(lp), 16, 0, 0)

// ---------- K1: u_t[h][p] = sum_d W_e[p][h*64+d] * w_rel[d]  (transposed) ----------
__global__ __launch_bounds__(256) void k_u(const float* __restrict__ W_e,
                                           const float* __restrict__ w_rel,
                                           float* __restrict__ u_t) {
    int e = blockIdx.x * 256 + threadIdx.x;
    if (e >= DEPC * HH) return;
    int p = e / HH, h = e % HH;
    const float4* we = (const float4*)(W_e + p * DD + h * 64);
    const float4* wr = (const float4*)w_rel;
    float acc = 0.f;
#pragma unroll
    for (int c = 0; c < 16; ++c) {
        float4 a = we[c], b = wr[c];
        acc += a.x * b.x + a.y * b.y + a.z * b.z + a.w * b.w;
    }
    u_t[h * DEPC + p] = acc;
}

// ---------- K2: V = token @ W_v.  32x32 tiles, grid 768 (3 blocks/CU) ----------
#define TM 32
#define TN 32
#define TKK 16
__global__ __launch_bounds__(256) void k_v(const float* __restrict__ A,
                                           const float* __restrict__ Bm,
                                           float* __restrict__ C) {
    __shared__ float As[TKK][TM + 1];  // [k][row]
    __shared__ float Bs[TKK][TN];      // [k][col]
    int t = threadIdx.x;
    int r = t >> 3, c4 = t & 7;        // output: row r, cols 4*c4..4*c4+3
    int r0 = blockIdx.x * TM, c0 = blockIdx.y * TN;
    float acc[4] = {};
    int sa = t & 127, isB = t >> 7;
    int ar = sa >> 2, aq = sa & 3;     // A: row, k-quad
    int bk = sa >> 3, bq = sa & 7;     // B: k, col-quad

    if (!isB) {
        float4 v = *(const float4*)&A[(r0 + ar) * DD + 4 * aq];
#pragma unroll
        for (int m = 0; m < 4; ++m) As[4 * aq + m][ar] = ((const float*)&v)[m];
    } else {
        *(float4*)&Bs[bk][4 * bq] = *(const float4*)&Bm[bk * DD + c0 + 4 * bq];
    }
    __syncthreads();

    for (int k0 = 0; k0 < DD; k0 += TKK) {
        float4 nx = {0, 0, 0, 0};
        if (k0 + TKK < DD) {
            int kn = k0 + TKK;
            nx = isB ? *(const float4*)&Bm[(kn + bk) * DD + c0 + 4 * bq]
                     : *(const float4*)&A[(r0 + ar) * DD + kn + 4 * aq];
        }
#pragma unroll
        for (int kk = 0; kk < TKK; ++kk) {
            float a = As[kk][r];
            float4 b = *(const float4*)&Bs[kk][4 * c4];
            acc[0] += a * b.x; acc[1] += a * b.y;
            acc[2] += a * b.z; acc[3] += a * b.w;
        }
        __syncthreads();
        if (k0 + TKK < DD) {
            if (!isB) {
#pragma unroll
                for (int m = 0; m < 4; ++m) As[4 * aq + m][ar] = ((const float*)&nx)[m];
            } else {
                *(float4*)&Bs[bk][4 * bq] = nx;
            }
        }
        __syncthreads();
    }
    *(float4*)&C[(size_t)(r0 + r) * DD + c0 + 4 * c4] =
        make_float4(acc[0], acc[1], acc[2], acc[3]);
}

// ---------- K3: scores — INDEPENDENT WAVES, zero barriers ----------
// Wave = 64 j-rows x all 12 heads. Private LDS slice, two 52-wide halves
// (stride 52 = 2-way banks, free). All 26 gload_lds + mask issued upfront;
// two wave-local counted vmcnt waits. u via compile-time-offset s_load.
__global__ __launch_bounds__(128) void k_sc(const float* __restrict__ edge,
                                            const int* __restrict__ mask,
                                            const float* __restrict__ ut,
                                            float* __restrict__ scores) {
    __shared__ float buf[2][6656];  // per wave: [0..3327]=h0 (p 0..51), [3328..6655]=h1 (p 48..99)
    int t = threadIdx.x;
    int lane = t & 63, w = t >> 6;
    int i = blockIdx.x, b = blockIdx.y;
    int jbase = blockIdx.z * 128 + w * 64;
    const float* src = edge + ((size_t)(b * SS + i) * SS + jbase) * DEPC;

    int mk = mask[(size_t)(b * SS + i) * SS + jbase + lane];  // vm #1
    __builtin_amdgcn_sched_barrier(0);
    // half0: rows [64][52] from p=0; elem E = call*256+lane*4; row=E/52 col=E%52
#pragma unroll
    for (int call = 0; call < 13; ++call) {
        int E = call * 256 + lane * 4;
        int row = E / 52, col = E - row * 52;
        GLDS(src + row * DEPC + col, &buf[w][call * 256]);
    }
    __builtin_amdgcn_sched_barrier(0);
    // half1: rows [64][52] from p=48
#pragma unroll
    for (int call = 0; call < 13; ++call) {
        int E = call * 256 + lane * 4;
        int row = E / 52, col = E - row * 52;
        GLDS(src + row * DEPC + 48 + col, &buf[w][3328 + call * 256]);
    }
    __builtin_amdgcn_sched_barrier(0);

    float acc[HH];
#pragma unroll
    for (int h = 0; h < HH; ++h) acc[h] = 0.f;

    // wait mask + half0 (13 of half1 still in flight)
    asm volatile("s_waitcnt vmcnt(13)" ::: "memory");
    __builtin_amdgcn_sched_barrier(0);

    const float* r0 = &buf[w][lane * 52];
#pragma unroll
    for (int p4 = 0; p4 < 13; ++p4) {        // p = 0..51
        float4 e4 = *(const float4*)(r0 + 4 * p4);
#pragma unroll
        for (int h = 0; h < HH; ++h) {
            const float* up = ut + h * DEPC + 4 * p4;   // s_load (uniform)
            acc[h] += e4.x * up[0] + e4.y * up[1] + e4.z * up[2] + e4.w * up[3];
        }
    }
    __builtin_amdgcn_sched_barrier(0);
    asm volatile("s_waitcnt vmcnt(0)" ::: "memory");
    __builtin_amdgcn_sched_barrier(0);

    const float* r1 = &buf[w][3328 + lane * 52];
#pragma unroll
    for (int p4 = 0; p4 < 12; ++p4) {        // p = 52..99 (skip first quad = 48..51)
        float4 e4 = *(const float4*)(r1 + 4 + 4 * p4);
#pragma unroll
        for (int h = 0; h < HH; ++h) {
            const float* up = ut + h * DEPC + 52 + 4 * p4;
            acc[h] += e4.x * up[0] + e4.y * up[1] + e4.z * up[2] + e4.w * up[3];
        }
    }

    int j = jbase + lane;
    size_t sb = ((size_t)b * HH * SS + i) * SS + j;
#pragma unroll
    for (int h = 0; h < HH; ++h)
        scores[sb + (size_t)h * SS * SS] = mk ? fmaxf(acc[h], 0.f) : -1e6f;
}

// ---------- K4: softmax + ctx, 512 threads (j-range split across halves) ----------
#define GG 4
__global__ __launch_bounds__(512) void k_ctx(const float* __restrict__ scores,
                                             const float* __restrict__ V,
                                             const float* __restrict__ token,
                                             float* __restrict__ out) {
    __shared__ float sc[GG][HH][SS];  // 48 KB
    __shared__ float red[GG][DD];     // 12.3 KB partials
    int t = threadIdx.x, b = blockIdx.y, i0 = blockIdx.x * GG;
    for (int idx = t; idx < GG * HH * (SS / 4); idx += 512) {
        int jc = idx & 63, rr = idx >> 6;
        int g = rr / HH, h = rr % HH;
        float4 v = *(const float4*)(scores + (((size_t)b * HH + h) * SS + (i0 + g)) * SS + 4 * jc);
        *(float4*)&sc[g][h][4 * jc] = v;
    }
    __syncthreads();
    int lane = t & 63, w = t >> 6;  // 8 waves
    for (int rr = w; rr < GG * HH; rr += 8) {
        int g = rr / HH, h = rr % HH;
        float x0 = sc[g][h][lane],       x1 = sc[g][h][lane + 64];
        float x2 = sc[g][h][lane + 128], x3 = sc[g][h][lane + 192];
        float m = fmaxf(fmaxf(x0, x1), fmaxf(x2, x3));
#pragma unroll
        for (int o = 32; o > 0; o >>= 1) m = fmaxf(m, __shfl_xor(m, o, 64));
        x0 = __expf(x0 - m); x1 = __expf(x1 - m);
        x2 = __expf(x2 - m); x3 = __expf(x3 - m);
        float s = x0 + x1 + x2 + x3;
#pragma unroll
        for (int o = 32; o > 0; o >>= 1) s += __shfl_xor(s, o, 64);
        float inv = 1.0f / s;
        sc[g][h][lane] = x0 * inv;       sc[g][h][lane + 64] = x1 * inv;
        sc[g][h][lane + 128] = x2 * inv; sc[g][h][lane + 192] = x3 * inv;
    }
    __syncthreads();
    int half = t >> 8, tt = t & 255;
    float acc[3][GG] = {};
    for (int j0 = half * 128; j0 < half * 128 + 128; j0 += 4) {
#pragma unroll
        for (int a = 0; a < 3; ++a) {
            int hd = tt + 256 * a;
            int h = hd >> 6;
            float v0 = V[(size_t)(b * SS + j0) * DD + hd];
            float v1 = V[(size_t)(b * SS + j0 + 1) * DD + hd];
            float v2 = V[(size_t)(b * SS + j0 + 2) * DD + hd];
            float v3 = V[(size_t)(b * SS + j0 + 3) * DD + hd];
#pragma unroll
            for (int g = 0; g < GG; ++g) {
                float4 p = *(const float4*)&sc[g][h][j0];
                acc[a][g] += p.x * v0 + p.y * v1 + p.z * v2 + p.w * v3;
            }
        }
    }
    if (half == 1) {
#pragma unroll
        for (int a = 0; a < 3; ++a)
#pragma unroll
            for (int g = 0; g < GG; ++g) red[g][tt + 256 * a] = acc[a][g];
    }
    __syncthreads();
    if (half == 0) {
#pragma unroll
        for (int a = 0; a < 3; ++a) {
            int hd = tt + 256 * a;
#pragma unroll
            for (int g = 0; g < GG; ++g) {
                size_t o = (size_t)(b * SS + i0 + g) * DD + hd;
                out[o] = fmaxf(token[o] + acc[a][g] + red[g][hd], 0.f);
            }
        }
    }
}

extern "C" void kernel_launch(void* const* d_in, const int* in_sizes, int n_in,
                              void* d_out, int out_size, void* d_ws, size_t ws_size,
                              hipStream_t stream) {
    const float* token = (const float*)d_in[0];
    const float* edge  = (const float*)d_in[1];
    const int*   mask  = (const int*)d_in[2];
    const float* W_v   = (const float*)d_in[3];
    const float* W_e   = (const float*)d_in[4];
    const float* w_rel = (const float*)d_in[5];
    float* out = (float*)d_out;

    char* ws = (char*)d_ws;
    float* u_t    = (float*)(ws);                                   // 4.8 KB
    float* V      = (float*)(ws + 8192);                            // 3.15 MB
    float* scores = (float*)(ws + 8192 + (size_t)BB * SS * DD * 4); // 12.6 MB

    hipLaunchKernelGGL(k_u,   dim3((DEPC * HH + 255) / 256), dim3(256), 0, stream, W_e, w_rel, u_t);
    hipLaunchKernelGGL(k_v,   dim3((BB * SS) / TM, DD / TN), dim3(256), 0, stream, token, W_v, V);
    hipLaunchKernelGGL(k_sc,  dim3(SS, BB, 2),               dim3(128), 0, stream, edge, mask, u_t, scores);
    hipLaunchKernelGGL(k_ctx, dim3(SS / GG, BB),             dim3(512), 0, stream, scores, V, token, out);
}

// Round 12
// 86.090 us; speedup vs baseline: 1.6475x; 1.2434x over previous
//
#include <hip/hip_runtime.h>
#include <math.h>

#define BB 4
#define SS 256
#define DD 768
#define DEPC 100
#define HH 12

typedef short bf16x8 __attribute__((ext_vector_type(8)));
typedef float f32x4 __attribute__((ext_vector_type(4)));

#define GLDS(gp, lp)                                                        \
    __builtin_amdgcn_global_load_lds(                                       \
        (const __attribute__((address_space(1))) void*)(gp),                \
        (__attribute__((address_space(3))) void*)(lp), 16, 0, 0)

__device__ __forceinline__ unsigned short f2bf(float x) {
    unsigned int u = __float_as_uint(x);
    u += 0x7FFF + ((u >> 16) & 1);
    return (unsigned short)(u >> 16);
}

// ---------- K1: u_t[h][p] = sum_d W_e[p][h*64+d] * w_rel[d]  (transposed) ----------
__global__ __launch_bounds__(256) void k_u(const float* __restrict__ W_e,
                                           const float* __restrict__ w_rel,
                                           float* __restrict__ u_t) {
    int e = blockIdx.x * 256 + threadIdx.x;
    if (e >= DEPC * HH) return;
    int p = e / HH, h = e % HH;
    const float4* we = (const float4*)(W_e + p * DD + h * 64);
    const float4* wr = (const float4*)w_rel;
    float acc = 0.f;
#pragma unroll
    for (int c = 0; c < 16; ++c) {
        float4 a = we[c], b = wr[c];
        acc += a.x * b.x + a.y * b.y + a.z * b.z + a.w * b.w;
    }
    u_t[h * DEPC + p] = acc;
}

// ---------- K1b: pack u into MFMA B-fragments (hi/lo bf16), zero-padded ----------
// Fragment order for 16x16x32 bf16: lane l supplies B[k = 32*s + (l>>4)*8 + e][col = l&15].
__global__ __launch_bounds__(256) void k_up(const float* __restrict__ u_t,
                                            unsigned short* __restrict__ upk) {
    int t = threadIdx.x;
    int s = t >> 6, l = t & 63;
    int h = l & 15, kg = l >> 4;
    unsigned short hi[8], lo[8];
#pragma unroll
    for (int e = 0; e < 8; ++e) {
        int k = 32 * s + kg * 8 + e;
        float v = (h < HH && k < DEPC) ? u_t[h * DEPC + k] : 0.f;
        unsigned short hb = f2bf(v);
        float hf = __uint_as_float(((unsigned int)hb) << 16);
        hi[e] = f2bf(v - hf) ? f2bf(v) : f2bf(v);  // keep simple: recompute below
        hi[e] = hb;
        lo[e] = f2bf(v - hf);
    }
    // hi plane at [0 .. 2048), lo plane at [2048 .. 4096) shorts
    unsigned short* dh = upk + (s * 64 + l) * 8;
    unsigned short* dl = upk + 2048 + (s * 64 + l) * 8;
#pragma unroll
    for (int e = 0; e < 8; ++e) { dh[e] = hi[e]; dl[e] = lo[e]; }
}

// ---------- K2: V = token @ W_v, double-buffered (R7 version) ----------
#define TM 32
#define TN 64
#define TKK 16
__global__ __launch_bounds__(256) void k_v(const float* __restrict__ A,
                                           const float* __restrict__ Bm,
                                           float* __restrict__ C) {
    __shared__ float As[TKK][TM + 4];
    __shared__ float Bs[TKK][TN];
    int t = threadIdx.x;
    int tx = t & 15, ty = t >> 4;
    int kb = t >> 6, cb = t & 63;
    int r0 = blockIdx.x * TM, c0 = blockIdx.y * TN;
    float acc[2][4] = {};

    As[tx][ty]      = A[(r0 + ty) * DD + tx];
    As[tx][ty + 16] = A[(r0 + ty + 16) * DD + tx];
#pragma unroll
    for (int q = 0; q < 4; ++q)
        Bs[kb + 4 * q][cb] = Bm[(kb + 4 * q) * DD + c0 + cb];
    __syncthreads();

    for (int k0 = 0; k0 < DD; k0 += TKK) {
        float an0 = 0.f, an1 = 0.f, bn[4] = {};
        if (k0 + TKK < DD) {
            int kn = k0 + TKK;
            an0 = A[(r0 + ty) * DD + kn + tx];
            an1 = A[(r0 + ty + 16) * DD + kn + tx];
#pragma unroll
            for (int q = 0; q < 4; ++q)
                bn[q] = Bm[(kn + kb + 4 * q) * DD + c0 + cb];
        }
#pragma unroll
        for (int kk = 0; kk < TKK; ++kk) {
            float a0 = As[kk][2 * ty], a1 = As[kk][2 * ty + 1];
            float4 b = *(const float4*)&Bs[kk][4 * tx];
            acc[0][0] += a0 * b.x; acc[0][1] += a0 * b.y;
            acc[0][2] += a0 * b.z; acc[0][3] += a0 * b.w;
            acc[1][0] += a1 * b.x; acc[1][1] += a1 * b.y;
            acc[1][2] += a1 * b.z; acc[1][3] += a1 * b.w;
        }
        __syncthreads();
        if (k0 + TKK < DD) {
            As[tx][ty]      = an0;
            As[tx][ty + 16] = an1;
#pragma unroll
            for (int q = 0; q < 4; ++q) Bs[kb + 4 * q][cb] = bn[q];
        }
        __syncthreads();
    }
#pragma unroll
    for (int m = 0; m < 2; ++m) {
        float4 v = make_float4(acc[m][0], acc[m][1], acc[m][2], acc[m][3]);
        *(float4*)&C[(size_t)(r0 + 2 * ty + m) * DD + c0 + 4 * tx] = v;
    }
}

// ---------- K3: scores via MFMA.  64-row chunk @ u-fragments, split-bf16 fp32 accuracy ----------
__global__ __launch_bounds__(256) void k_sc(const float* __restrict__ edge,
                                            const int* __restrict__ mask,
                                            const unsigned short* __restrict__ upk,
                                            float* __restrict__ scores) {
    __shared__ float buf[64 * DEPC + 32];  // linear [64][100] + zeroed pad
    int t = threadIdx.x;
    int jc = blockIdx.x & 3;
    int i  = blockIdx.x >> 2;
    int b  = blockIdx.y;
    int lane = t & 63, w = t >> 6;

    const float* src = edge + (size_t)((b * SS + i) * SS + jc * 64) * DEPC;
    for (int call = w; call < 25; call += 4)
        GLDS(src + call * 256 + lane * 4, &buf[call * 256]);
    if (t < 32) buf[6400 + t] = 0.f;  // pad: garbage*0 stays finite

    // u fragments: 4 k-steps x (hi, lo), 16B per lane each, coalesced
    bf16x8 uh[4], ul[4];
#pragma unroll
    for (int s = 0; s < 4; ++s) {
        uh[s] = *(const bf16x8*)(upk + (s * 64 + lane) * 8);
        ul[s] = *(const bf16x8*)(upk + 2048 + (s * 64 + lane) * 8);
    }
    __syncthreads();

    // wave w computes rows [w*16, w*16+16) of the 64-row chunk
    int arow = lane & 15, kg = lane >> 4;
    const float* rbase = buf + (w * 16 + arow) * DEPC;
    f32x4 acc = {0.f, 0.f, 0.f, 0.f};
#pragma unroll
    for (int s = 0; s < 4; ++s) {
        const float4* p = (const float4*)(rbase + 32 * s + kg * 8);
        float4 va = p[0], vb = p[1];
        float ev[8] = {va.x, va.y, va.z, va.w, vb.x, vb.y, vb.z, vb.w};
        bf16x8 ehi, elo;
#pragma unroll
        for (int e = 0; e < 8; ++e) {
            unsigned short hb = f2bf(ev[e]);
            ehi[e] = (short)hb;
            float hf = __uint_as_float(((unsigned int)hb) << 16);
            elo[e] = (short)f2bf(ev[e] - hf);
        }
        acc = __builtin_amdgcn_mfma_f32_16x16x32_bf16(ehi, uh[s], acc, 0, 0, 0);
        acc = __builtin_amdgcn_mfma_f32_16x16x32_bf16(ehi, ul[s], acc, 0, 0, 0);
        acc = __builtin_amdgcn_mfma_f32_16x16x32_bf16(elo, uh[s], acc, 0, 0, 0);
    }

    // D: col = lane&15 = h, row = (lane>>4)*4 + r = j-offset within tile (m89)
    int h = lane & 15;
    int j0 = jc * 64 + w * 16 + (lane >> 4) * 4;
    int4 mk = *(const int4*)(mask + (size_t)(b * SS + i) * SS + j0);
    float4 r;
    r.x = mk.x ? fmaxf(acc[0], 0.f) : -1e6f;
    r.y = mk.y ? fmaxf(acc[1], 0.f) : -1e6f;
    r.z = mk.z ? fmaxf(acc[2], 0.f) : -1e6f;
    r.w = mk.w ? fmaxf(acc[3], 0.f) : -1e6f;
    if (h < HH)
        *(float4*)&scores[(((size_t)b * HH + h) * SS + i) * SS + j0] = r;
}

// ---------- K4: softmax + ctx, 512 threads (j-range split across halves) ----------
#define GG 4
__global__ __launch_bounds__(512) void k_ctx(const float* __restrict__ scores,
                                             const float* __restrict__ V,
                                             const float* __restrict__ token,
                                             float* __restrict__ out) {
    __shared__ float sc[GG][HH][SS];  // 48 KB
    __shared__ float red[GG][DD];     // 12.3 KB partials
    int t = threadIdx.x, b = blockIdx.y, i0 = blockIdx.x * GG;
    for (int idx = t; idx < GG * HH * (SS / 4); idx += 512) {
        int jc = idx & 63, rr = idx >> 6;
        int g = rr / HH, h = rr % HH;
        float4 v = *(const float4*)(scores + (((size_t)b * HH + h) * SS + (i0 + g)) * SS + 4 * jc);
        *(float4*)&sc[g][h][4 * jc] = v;
    }
    __syncthreads();
    int lane = t & 63, w = t >> 6;  // 8 waves
    for (int rr = w; rr < GG * HH; rr += 8) {
        int g = rr / HH, h = rr % HH;
        float x0 = sc[g][h][lane],       x1 = sc[g][h][lane + 64];
        float x2 = sc[g][h][lane + 128], x3 = sc[g][h][lane + 192];
        float m = fmaxf(fmaxf(x0, x1), fmaxf(x2, x3));
#pragma unroll
        for (int o = 32; o > 0; o >>= 1) m = fmaxf(m, __shfl_xor(m, o, 64));
        x0 = __expf(x0 - m); x1 = __expf(x1 - m);
        x2 = __expf(x2 - m); x3 = __expf(x3 - m);
        float s = x0 + x1 + x2 + x3;
#pragma unroll
        for (int o = 32; o > 0; o >>= 1) s += __shfl_xor(s, o, 64);
        float inv = 1.0f / s;
        sc[g][h][lane] = x0 * inv;       sc[g][h][lane + 64] = x1 * inv;
        sc[g][h][lane + 128] = x2 * inv; sc[g][h][lane + 192] = x3 * inv;
    }
    __syncthreads();
    int half = t >> 8, tt = t & 255;
    float acc[3][GG] = {};
    for (int j0 = half * 128; j0 < half * 128 + 128; j0 += 4) {
#pragma unroll
        for (int a = 0; a < 3; ++a) {
            int hd = tt + 256 * a;
            int h = hd >> 6;
            float v0 = V[(size_t)(b * SS + j0) * DD + hd];
            float v1 = V[(size_t)(b * SS + j0 + 1) * DD + hd];
            float v2 = V[(size_t)(b * SS + j0 + 2) * DD + hd];
            float v3 = V[(size_t)(b * SS + j0 + 3) * DD + hd];
#pragma unroll
            for (int g = 0; g < GG; ++g) {
                float4 p = *(const float4*)&sc[g][h][j0];
                acc[a][g] += p.x * v0 + p.y * v1 + p.z * v2 + p.w * v3;
            }
        }
    }
    if (half == 1) {
#pragma unroll
        for (int a = 0; a < 3; ++a)
#pragma unroll
            for (int g = 0; g < GG; ++g) red[g][tt + 256 * a] = acc[a][g];
    }
    __syncthreads();
    if (half == 0) {
#pragma unroll
        for (int a = 0; a < 3; ++a) {
            int hd = tt + 256 * a;
#pragma unroll
            for (int g = 0; g < GG; ++g) {
                size_t o = (size_t)(b * SS + i0 + g) * DD + hd;
                out[o] = fmaxf(token[o] + acc[a][g] + red[g][hd], 0.f);
            }
        }
    }
}

extern "C" void kernel_launch(void* const* d_in, const int* in_sizes, int n_in,
                              void* d_out, int out_size, void* d_ws, size_t ws_size,
                              hipStream_t stream) {
    const float* token = (const float*)d_in[0];
    const float* edge  = (const float*)d_in[1];
    const int*   mask  = (const int*)d_in[2];
    const float* W_v   = (const float*)d_in[3];
    const float* W_e   = (const float*)d_in[4];
    const float* w_rel = (const float*)d_in[5];
    float* out = (float*)d_out;

    char* ws = (char*)d_ws;
    float* u_t            = (float*)(ws);                     // 4.8 KB
    unsigned short* upk   = (unsigned short*)(ws + 8192);     // 8 KB (hi+lo)
    float* V              = (float*)(ws + 16384);             // 3.15 MB
    float* scores         = (float*)(ws + 16384 + (size_t)BB * SS * DD * 4);  // 12.6 MB

    hipLaunchKernelGGL(k_u,   dim3((DEPC * HH + 255) / 256), dim3(256), 0, stream, W_e, w_rel, u_t);
    hipLaunchKernelGGL(k_up,  dim3(1),                       dim3(256), 0, stream, u_t, upk);
    hipLaunchKernelGGL(k_v,   dim3((BB * SS) / TM, DD / TN), dim3(256), 0, stream, token, W_v, V);
    hipLaunchKernelGGL(k_sc,  dim3(SS * 4, BB),              dim3(256), 0, stream, edge, mask, upk, scores);
    hipLaunchKernelGGL(k_ctx, dim3(SS / GG, BB),             dim3(512), 0, stream, scores, V, token, out);
}

// Round 13
// 69.043 us; speedup vs baseline: 2.0543x; 1.2469x over previous
//
#include <hip/hip_runtime.h>
#include <math.h>

#define BB 4
#define SS 256
#define DD 768
#define DEPC 100
#define HH 12

typedef short bf16x8 __attribute__((ext_vector_type(8)));
typedef float f32x4 __attribute__((ext_vector_type(4)));

#define GLDS(gp, lp)                                                        \
    __builtin_amdgcn_global_load_lds(                                       \
        (const __attribute__((address_space(1))) void*)(gp),                \
        (__attribute__((address_space(3))) void*)(lp), 16, 0, 0)

__device__ __forceinline__ unsigned short f2bf(float x) {
    unsigned int u = __float_as_uint(x);
    u += 0x7FFF + ((u >> 16) & 1);
    return (unsigned short)(u >> 16);
}
__device__ __forceinline__ float bf2f(unsigned short h) {
    return __uint_as_float(((unsigned int)h) << 16);
}

// ---------- K1: u_t[h][p] = sum_d W_e[p][h*64+d] * w_rel[d]  (transposed) ----------
__global__ __launch_bounds__(256) void k_u(const float* __restrict__ W_e,
                                           const float* __restrict__ w_rel,
                                           float* __restrict__ u_t) {
    int e = blockIdx.x * 256 + threadIdx.x;
    if (e >= DEPC * HH) return;
    int p = e / HH, h = e % HH;
    const float4* we = (const float4*)(W_e + p * DD + h * 64);
    const float4* wr = (const float4*)w_rel;
    float acc = 0.f;
#pragma unroll
    for (int c = 0; c < 16; ++c) {
        float4 a = we[c], b = wr[c];
        acc += a.x * b.x + a.y * b.y + a.z * b.z + a.w * b.w;
    }
    u_t[h * DEPC + p] = acc;
}

// ---------- K1b: pack u into MFMA B-fragments (hi/lo bf16), zero-padded ----------
__global__ __launch_bounds__(256) void k_up(const float* __restrict__ u_t,
                                            unsigned short* __restrict__ upk) {
    int t = threadIdx.x;
    int s = t >> 6, l = t & 63;
    int h = l & 15, kg = l >> 4;
    unsigned short hi[8], lo[8];
#pragma unroll
    for (int e = 0; e < 8; ++e) {
        int k = 32 * s + kg * 8 + e;
        float v = (h < HH && k < DEPC) ? u_t[h * DEPC + k] : 0.f;
        unsigned short hb = f2bf(v);
        hi[e] = hb;
        lo[e] = f2bf(v - bf2f(hb));
    }
    unsigned short* dh = upk + (s * 64 + l) * 8;
    unsigned short* dl = upk + 2048 + (s * 64 + l) * 8;
#pragma unroll
    for (int e = 0; e < 8; ++e) { dh[e] = hi[e]; dl[e] = lo[e]; }
}

// ---------- K1c: pack W_v into MFMA B-fragments (hi/lo bf16) ----------
// frag (s, ct): B[k = s*32 + kg*8 + e][col = ct*16 + cl], lane l: cl=l&15, kg=l>>4.
// layout: wpk[plane][ (s*48+ct)*64 + lane ][8], plane stride 589824 shorts.
__global__ __launch_bounds__(256) void k_wpk(const float* __restrict__ W,
                                             unsigned short* __restrict__ wpk) {
    int t = threadIdx.x;
    int unit = blockIdx.x * 4 + (t >> 6);
    int lane = t & 63;
    int s = unit / 48, ct = unit % 48;
    int cl = lane & 15, kg = lane >> 4;
    unsigned short hi[8], lo[8];
#pragma unroll
    for (int e = 0; e < 8; ++e) {
        int k = s * 32 + kg * 8 + e;
        float v = W[(size_t)k * DD + ct * 16 + cl];
        unsigned short hb = f2bf(v);
        hi[e] = hb;
        lo[e] = f2bf(v - bf2f(hb));
    }
    size_t base = ((size_t)(s * 48 + ct) * 64 + lane) * 8;
    unsigned short* dh = wpk + base;
    unsigned short* dl = wpk + 589824 + base;
#pragma unroll
    for (int e = 0; e < 8; ++e) { dh[e] = hi[e]; dl[e] = lo[e]; }
}

// ---------- K2: V = token @ W_v via MFMA (split-bf16), 32x32 tiles ----------
__global__ __launch_bounds__(256) void k_v(const float* __restrict__ A,
                                           const unsigned short* __restrict__ wpk,
                                           float* __restrict__ C) {
    __shared__ unsigned short Ah[2][32][40], Al[2][32][40];  // pad 8 -> 2-way banks
    int t = threadIdx.x;
    int lane = t & 63, w = t >> 6;
    int wr = w >> 1, wc = w & 1;
    int r0 = blockIdx.x * 32, c0y = blockIdx.y;
    int srow = t >> 3, sq = t & 7;

    // stage s = 0
    {
        float4 av = *(const float4*)&A[(size_t)(r0 + srow) * DD + 4 * sq];
        const float* af = (const float*)&av;
#pragma unroll
        for (int e = 0; e < 4; ++e) {
            unsigned short hb = f2bf(af[e]);
            Ah[0][srow][4 * sq + e] = hb;
            Al[0][srow][4 * sq + e] = f2bf(af[e] - bf2f(hb));
        }
    }
    __syncthreads();

    int ct = c0y * 2 + wc;
    int fr = wr * 16 + (lane & 15);
    int kg = lane >> 4;
    f32x4 acc = {0.f, 0.f, 0.f, 0.f};

    for (int s = 0; s < 24; ++s) {
        float4 nx = {0, 0, 0, 0};
        if (s + 1 < 24)
            nx = *(const float4*)&A[(size_t)(r0 + srow) * DD + (s + 1) * 32 + 4 * sq];

        const unsigned short* bp = wpk + ((size_t)(s * 48 + ct) * 64 + lane) * 8;
        bf16x8 bh = *(const bf16x8*)bp;
        bf16x8 bl = *(const bf16x8*)(bp + 589824);
        bf16x8 ah = *(const bf16x8*)&Ah[s & 1][fr][kg * 8];
        bf16x8 al = *(const bf16x8*)&Al[s & 1][fr][kg * 8];
        acc = __builtin_amdgcn_mfma_f32_16x16x32_bf16(ah, bh, acc, 0, 0, 0);
        acc = __builtin_amdgcn_mfma_f32_16x16x32_bf16(al, bh, acc, 0, 0, 0);
        acc = __builtin_amdgcn_mfma_f32_16x16x32_bf16(ah, bl, acc, 0, 0, 0);

        if (s + 1 < 24) {
            const float* nf = (const float*)&nx;
            int nb = (s + 1) & 1;
#pragma unroll
            for (int e = 0; e < 4; ++e) {
                unsigned short hb = f2bf(nf[e]);
                Ah[nb][srow][4 * sq + e] = hb;
                Al[nb][srow][4 * sq + e] = f2bf(nf[e] - bf2f(hb));
            }
        }
        __syncthreads();
    }

    int col = c0y * 32 + wc * 16 + (lane & 15);
    int rowb = r0 + wr * 16 + (lane >> 4) * 4;
#pragma unroll
    for (int e = 0; e < 4; ++e)
        C[(size_t)(rowb + e) * DD + col] = acc[e];
}

// ---------- K3: scores via MFMA (unchanged from R12) ----------
__global__ __launch_bounds__(256) void k_sc(const float* __restrict__ edge,
                                            const int* __restrict__ mask,
                                            const unsigned short* __restrict__ upk,
                                            float* __restrict__ scores) {
    __shared__ float buf[64 * DEPC + 32];
    int t = threadIdx.x;
    int jc = blockIdx.x & 3;
    int i  = blockIdx.x >> 2;
    int b  = blockIdx.y;
    int lane = t & 63, w = t >> 6;

    const float* src = edge + (size_t)((b * SS + i) * SS + jc * 64) * DEPC;
    for (int call = w; call < 25; call += 4)
        GLDS(src + call * 256 + lane * 4, &buf[call * 256]);
    if (t < 32) buf[6400 + t] = 0.f;

    bf16x8 uh[4], ul[4];
#pragma unroll
    for (int s = 0; s < 4; ++s) {
        uh[s] = *(const bf16x8*)(upk + (s * 64 + lane) * 8);
        ul[s] = *(const bf16x8*)(upk + 2048 + (s * 64 + lane) * 8);
    }
    __syncthreads();

    int arow = lane & 15, kg = lane >> 4;
    const float* rbase = buf + (w * 16 + arow) * DEPC;
    f32x4 acc = {0.f, 0.f, 0.f, 0.f};
#pragma unroll
    for (int s = 0; s < 4; ++s) {
        const float4* p = (const float4*)(rbase + 32 * s + kg * 8);
        float4 va = p[0], vb = p[1];
        float ev[8] = {va.x, va.y, va.z, va.w, vb.x, vb.y, vb.z, vb.w};
        bf16x8 ehi, elo;
#pragma unroll
        for (int e = 0; e < 8; ++e) {
            unsigned short hb = f2bf(ev[e]);
            ehi[e] = (short)hb;
            elo[e] = (short)f2bf(ev[e] - bf2f(hb));
        }
        acc = __builtin_amdgcn_mfma_f32_16x16x32_bf16(ehi, uh[s], acc, 0, 0, 0);
        acc = __builtin_amdgcn_mfma_f32_16x16x32_bf16(ehi, ul[s], acc, 0, 0, 0);
        acc = __builtin_amdgcn_mfma_f32_16x16x32_bf16(elo, uh[s], acc, 0, 0, 0);
    }

    int h = lane & 15;
    int j0 = jc * 64 + w * 16 + (lane >> 4) * 4;
    int4 mk = *(const int4*)(mask + (size_t)(b * SS + i) * SS + j0);
    float4 r;
    r.x = mk.x ? fmaxf(acc[0], 0.f) : -1e6f;
    r.y = mk.y ? fmaxf(acc[1], 0.f) : -1e6f;
    r.z = mk.z ? fmaxf(acc[2], 0.f) : -1e6f;
    r.w = mk.w ? fmaxf(acc[3], 0.f) : -1e6f;
    if (h < HH)
        *(float4*)&scores[(((size_t)b * HH + h) * SS + i) * SS + j0] = r;
}

// ---------- K4: softmax + ctx, 512 threads (unchanged) ----------
#define GG 4
__global__ __launch_bounds__(512) void k_ctx(const float* __restrict__ scores,
                                             const float* __restrict__ V,
                                             const float* __restrict__ token,
                                             float* __restrict__ out) {
    __shared__ float sc[GG][HH][SS];
    __shared__ float red[GG][DD];
    int t = threadIdx.x, b = blockIdx.y, i0 = blockIdx.x * GG;
    for (int idx = t; idx < GG * HH * (SS / 4); idx += 512) {
        int jc = idx & 63, rr = idx >> 6;
        int g = rr / HH, h = rr % HH;
        float4 v = *(const float4*)(scores + (((size_t)b * HH + h) * SS + (i0 + g)) * SS + 4 * jc);
        *(float4*)&sc[g][h][4 * jc] = v;
    }
    __syncthreads();
    int lane = t & 63, w = t >> 6;
    for (int rr = w; rr < GG * HH; rr += 8) {
        int g = rr / HH, h = rr % HH;
        float x0 = sc[g][h][lane],       x1 = sc[g][h][lane + 64];
        float x2 = sc[g][h][lane + 128], x3 = sc[g][h][lane + 192];
        float m = fmaxf(fmaxf(x0, x1), fmaxf(x2, x3));
#pragma unroll
        for (int o = 32; o > 0; o >>= 1) m = fmaxf(m, __shfl_xor(m, o, 64));
        x0 = __expf(x0 - m); x1 = __expf(x1 - m);
        x2 = __expf(x2 - m); x3 = __expf(x3 - m);
        float s = x0 + x1 + x2 + x3;
#pragma unroll
        for (int o = 32; o > 0; o >>= 1) s += __shfl_xor(s, o, 64);
        float inv = 1.0f / s;
        sc[g][h][lane] = x0 * inv;       sc[g][h][lane + 64] = x1 * inv;
        sc[g][h][lane + 128] = x2 * inv; sc[g][h][lane + 192] = x3 * inv;
    }
    __syncthreads();
    int half = t >> 8, tt = t & 255;
    float acc[3][GG] = {};
    for (int j0 = half * 128; j0 < half * 128 + 128; j0 += 4) {
#pragma unroll
        for (int a = 0; a < 3; ++a) {
            int hd = tt + 256 * a;
            int h = hd >> 6;
            float v0 = V[(size_t)(b * SS + j0) * DD + hd];
            float v1 = V[(size_t)(b * SS + j0 + 1) * DD + hd];
            float v2 = V[(size_t)(b * SS + j0 + 2) * DD + hd];
            float v3 = V[(size_t)(b * SS + j0 + 3) * DD + hd];
#pragma unroll
            for (int g = 0; g < GG; ++g) {
                float4 p = *(const float4*)&sc[g][h][j0];
                acc[a][g] += p.x * v0 + p.y * v1 + p.z * v2 + p.w * v3;
            }
        }
    }
    if (half == 1) {
#pragma unroll
        for (int a = 0; a < 3; ++a)
#pragma unroll
            for (int g = 0; g < GG; ++g) red[g][tt + 256 * a] = acc[a][g];
    }
    __syncthreads();
    if (half == 0) {
#pragma unroll
        for (int a = 0; a < 3; ++a) {
            int hd = tt + 256 * a;
#pragma unroll
            for (int g = 0; g < GG; ++g) {
                size_t o = (size_t)(b * SS + i0 + g) * DD + hd;
                out[o] = fmaxf(token[o] + acc[a][g] + red[g][hd], 0.f);
            }
        }
    }
}

extern "C" void kernel_launch(void* const* d_in, const int* in_sizes, int n_in,
                              void* d_out, int out_size, void* d_ws, size_t ws_size,
                              hipStream_t stream) {
    const float* token = (const float*)d_in[0];
    const float* edge  = (const float*)d_in[1];
    const int*   mask  = (const int*)d_in[2];
    const float* W_v   = (const float*)d_in[3];
    const float* W_e   = (const float*)d_in[4];
    const float* w_rel = (const float*)d_in[5];
    float* out = (float*)d_out;

    char* ws = (char*)d_ws;
    float* u_t          = (float*)(ws);                       // 4.8 KB
    unsigned short* upk = (unsigned short*)(ws + 8192);       // 8 KB
    unsigned short* wpk = (unsigned short*)(ws + 16384);      // 2.36 MB (hi+lo)
    float* V            = (float*)(ws + 16384 + 2359296);
    float* scores       = (float*)(ws + 16384 + 2359296 + (size_t)BB * SS * DD * 4);

    hipLaunchKernelGGL(k_u,   dim3((DEPC * HH + 255) / 256), dim3(256), 0, stream, W_e, w_rel, u_t);
    hipLaunchKernelGGL(k_up,  dim3(1),                       dim3(256), 0, stream, u_t, upk);
    hipLaunchKernelGGL(k_wpk, dim3(288),                     dim3(256), 0, stream, W_v, wpk);
    hipLaunchKernelGGL(k_v,   dim3(32, 24),                  dim3(256), 0, stream, token, wpk, V);
    hipLaunchKernelGGL(k_sc,  dim3(SS * 4, BB),              dim3(256), 0, stream, edge, mask, upk, scores);
    hipLaunchKernelGGL(k_ctx, dim3(SS / GG, BB),             dim3(512), 0, stream, scores, V, token, out);
}

// Round 14
// 58.153 us; speedup vs baseline: 2.4390x; 1.1873x over previous
//
#include <hip/hip_runtime.h>
#include <math.h>

#define BB 4
#define SS 256
#define DD 768
#define DEPC 100
#define HH 12

typedef short bf16x8 __attribute__((ext_vector_type(8)));
typedef float f32x4 __attribute__((ext_vector_type(4)));

#define GLDS(gp, lp)                                                        \
    __builtin_amdgcn_global_load_lds(                                       \
        (const __attribute__((address_space(1))) void*)(gp),                \
        (__attribute__((address_space(3))) void*)(lp), 16, 0, 0)

__device__ __forceinline__ unsigned short f2bf(float x) {
    unsigned int u = __float_as_uint(x);
    u += 0x7FFF + ((u >> 16) & 1);
    return (unsigned short)(u >> 16);
}
__device__ __forceinline__ float bf2f(unsigned short h) {
    return __uint_as_float(((unsigned int)h) << 16);
}

// ---------- K_prep: block 0 = u compute+pack; blocks 1..288 = W_v pack ----------
__global__ __launch_bounds__(256) void k_prep(const float* __restrict__ W_e,
                                              const float* __restrict__ w_rel,
                                              const float* __restrict__ W_v,
                                              unsigned short* __restrict__ upk,
                                              unsigned short* __restrict__ wpk) {
    int t = threadIdx.x;
    if (blockIdx.x == 0) {
        __shared__ float u_l[HH][DEPC];
        const float4* wr = (const float4*)w_rel;
        float4 wrv[16];
#pragma unroll
        for (int c = 0; c < 16; ++c) wrv[c] = wr[c];
        for (int e = t; e < DEPC * HH; e += 256) {
            int p = e / HH, h = e % HH;
            const float4* we = (const float4*)(W_e + p * DD + h * 64);
            float acc = 0.f;
#pragma unroll
            for (int c = 0; c < 16; ++c) {
                float4 a = we[c], b = wrv[c];
                acc += a.x * b.x + a.y * b.y + a.z * b.z + a.w * b.w;
            }
            u_l[h][p] = acc;
        }
        __syncthreads();
        int s = t >> 6, l = t & 63;
        int h = l & 15, kg = l >> 4;
        unsigned short hi[8], lo[8];
#pragma unroll
        for (int e = 0; e < 8; ++e) {
            int k = 32 * s + kg * 8 + e;
            float v = (h < HH && k < DEPC) ? u_l[h][k] : 0.f;
            unsigned short hb = f2bf(v);
            hi[e] = hb;
            lo[e] = f2bf(v - bf2f(hb));
        }
        unsigned short* dh = upk + (s * 64 + l) * 8;
        unsigned short* dl = upk + 2048 + (s * 64 + l) * 8;
#pragma unroll
        for (int e = 0; e < 8; ++e) { dh[e] = hi[e]; dl[e] = lo[e]; }
    } else {
        int unit = (blockIdx.x - 1) * 4 + (t >> 6);
        int lane = t & 63;
        int s = unit / 48, ct = unit % 48;
        int cl = lane & 15, kg = lane >> 4;
        unsigned short hi[8], lo[8];
#pragma unroll
        for (int e = 0; e < 8; ++e) {
            int k = s * 32 + kg * 8 + e;
            float v = W_v[(size_t)k * DD + ct * 16 + cl];
            unsigned short hb = f2bf(v);
            hi[e] = hb;
            lo[e] = f2bf(v - bf2f(hb));
        }
        size_t base = ((size_t)(s * 48 + ct) * 64 + lane) * 8;
        unsigned short* dh = wpk + base;
        unsigned short* dl = wpk + 589824 + base;
#pragma unroll
        for (int e = 0; e < 8; ++e) { dh[e] = hi[e]; dl[e] = lo[e]; }
    }
}

// ---------- K2: V = token @ W_v via MFMA (split-bf16) -> bf16 output ----------
__global__ __launch_bounds__(256) void k_v(const float* __restrict__ A,
                                           const unsigned short* __restrict__ wpk,
                                           unsigned short* __restrict__ Vbf) {
    __shared__ unsigned short Ah[2][32][40], Al[2][32][40];
    int t = threadIdx.x;
    int lane = t & 63, w = t >> 6;
    int wr = w >> 1, wc = w & 1;
    int r0 = blockIdx.x * 32, c0y = blockIdx.y;
    int srow = t >> 3, sq = t & 7;

    {
        float4 av = *(const float4*)&A[(size_t)(r0 + srow) * DD + 4 * sq];
        const float* af = (const float*)&av;
#pragma unroll
        for (int e = 0; e < 4; ++e) {
            unsigned short hb = f2bf(af[e]);
            Ah[0][srow][4 * sq + e] = hb;
            Al[0][srow][4 * sq + e] = f2bf(af[e] - bf2f(hb));
        }
    }
    __syncthreads();

    int ct = c0y * 2 + wc;
    int fr = wr * 16 + (lane & 15);
    int kg = lane >> 4;
    f32x4 acc = {0.f, 0.f, 0.f, 0.f};

    for (int s = 0; s < 24; ++s) {
        float4 nx = {0, 0, 0, 0};
        if (s + 1 < 24)
            nx = *(const float4*)&A[(size_t)(r0 + srow) * DD + (s + 1) * 32 + 4 * sq];

        const unsigned short* bp = wpk + ((size_t)(s * 48 + ct) * 64 + lane) * 8;
        bf16x8 bh = *(const bf16x8*)bp;
        bf16x8 bl = *(const bf16x8*)(bp + 589824);
        bf16x8 ah = *(const bf16x8*)&Ah[s & 1][fr][kg * 8];
        bf16x8 al = *(const bf16x8*)&Al[s & 1][fr][kg * 8];
        acc = __builtin_amdgcn_mfma_f32_16x16x32_bf16(ah, bh, acc, 0, 0, 0);
        acc = __builtin_amdgcn_mfma_f32_16x16x32_bf16(al, bh, acc, 0, 0, 0);
        acc = __builtin_amdgcn_mfma_f32_16x16x32_bf16(ah, bl, acc, 0, 0, 0);

        if (s + 1 < 24) {
            const float* nf = (const float*)&nx;
            int nb = (s + 1) & 1;
#pragma unroll
            for (int e = 0; e < 4; ++e) {
                unsigned short hb = f2bf(nf[e]);
                Ah[nb][srow][4 * sq + e] = hb;
                Al[nb][srow][4 * sq + e] = f2bf(nf[e] - bf2f(hb));
            }
        }
        __syncthreads();
    }

    int col = c0y * 32 + wc * 16 + (lane & 15);
    int rowb = r0 + wr * 16 + (lane >> 4) * 4;
#pragma unroll
    for (int e = 0; e < 4; ++e)
        Vbf[(size_t)(rowb + e) * DD + col] = f2bf(acc[e]);
}

// ---------- K3: scores via MFMA (unchanged from R12/R13) ----------
__global__ __launch_bounds__(256) void k_sc(const float* __restrict__ edge,
                                            const int* __restrict__ mask,
                                            const unsigned short* __restrict__ upk,
                                            float* __restrict__ scores) {
    __shared__ float buf[64 * DEPC + 32];
    int t = threadIdx.x;
    int jc = blockIdx.x & 3;
    int i  = blockIdx.x >> 2;
    int b  = blockIdx.y;
    int lane = t & 63, w = t >> 6;

    const float* src = edge + (size_t)((b * SS + i) * SS + jc * 64) * DEPC;
    for (int call = w; call < 25; call += 4)
        GLDS(src + call * 256 + lane * 4, &buf[call * 256]);
    if (t < 32) buf[6400 + t] = 0.f;

    bf16x8 uh[4], ul[4];
#pragma unroll
    for (int s = 0; s < 4; ++s) {
        uh[s] = *(const bf16x8*)(upk + (s * 64 + lane) * 8);
        ul[s] = *(const bf16x8*)(upk + 2048 + (s * 64 + lane) * 8);
    }
    __syncthreads();

    int arow = lane & 15, kg = lane >> 4;
    const float* rbase = buf + (w * 16 + arow) * DEPC;
    f32x4 acc = {0.f, 0.f, 0.f, 0.f};
#pragma unroll
    for (int s = 0; s < 4; ++s) {
        const float4* p = (const float4*)(rbase + 32 * s + kg * 8);
        float4 va = p[0], vb = p[1];
        float ev[8] = {va.x, va.y, va.z, va.w, vb.x, vb.y, vb.z, vb.w};
        bf16x8 ehi, elo;
#pragma unroll
        for (int e = 0; e < 8; ++e) {
            unsigned short hb = f2bf(ev[e]);
            ehi[e] = (short)hb;
            elo[e] = (short)f2bf(ev[e] - bf2f(hb));
        }
        acc = __builtin_amdgcn_mfma_f32_16x16x32_bf16(ehi, uh[s], acc, 0, 0, 0);
        acc = __builtin_amdgcn_mfma_f32_16x16x32_bf16(ehi, ul[s], acc, 0, 0, 0);
        acc = __builtin_amdgcn_mfma_f32_16x16x32_bf16(elo, uh[s], acc, 0, 0, 0);
    }

    int h = lane & 15;
    int j0 = jc * 64 + w * 16 + (lane >> 4) * 4;
    int4 mk = *(const int4*)(mask + (size_t)(b * SS + i) * SS + j0);
    float4 r;
    r.x = mk.x ? fmaxf(acc[0], 0.f) : -1e6f;
    r.y = mk.y ? fmaxf(acc[1], 0.f) : -1e6f;
    r.z = mk.z ? fmaxf(acc[2], 0.f) : -1e6f;
    r.w = mk.w ? fmaxf(acc[3], 0.f) : -1e6f;
    if (h < HH)
        *(float4*)&scores[(((size_t)b * HH + h) * SS + i) * SS + j0] = r;
}

// ---------- K4: softmax + PV via MFMA.  Block = (i-tile16, h, b) ----------
__global__ __launch_bounds__(256) void k_ctx(const float* __restrict__ scores,
                                             const unsigned short* __restrict__ Vbf,
                                             const float* __restrict__ token,
                                             float* __restrict__ out) {
    __shared__ float P[16][260];           // fp32 scores/softmax workspace
    __shared__ unsigned short Pb[16][264]; // bf16 probs (A-fragments)
    int t = threadIdx.x;
    int i0 = blockIdx.x * 16, h = blockIdx.y, b = blockIdx.z;
    int lane = t & 63, w = t >> 6;

    const float* sbase = scores + (((size_t)b * HH + h) * SS + i0) * SS;
#pragma unroll
    for (int k = 0; k < 4; ++k) {
        int idx = t + 256 * k;
        int r = idx >> 6, jc = idx & 63;
        float4 v = *(const float4*)(sbase + (size_t)r * SS + 4 * jc);
        *(float4*)&P[r][4 * jc] = v;
    }
    __syncthreads();

    for (int r = w; r < 16; r += 4) {
        float x0 = P[r][lane],       x1 = P[r][lane + 64];
        float x2 = P[r][lane + 128], x3 = P[r][lane + 192];
        float m = fmaxf(fmaxf(x0, x1), fmaxf(x2, x3));
#pragma unroll
        for (int o = 32; o > 0; o >>= 1) m = fmaxf(m, __shfl_xor(m, o, 64));
        x0 = __expf(x0 - m); x1 = __expf(x1 - m);
        x2 = __expf(x2 - m); x3 = __expf(x3 - m);
        float s = x0 + x1 + x2 + x3;
#pragma unroll
        for (int o = 32; o > 0; o >>= 1) s += __shfl_xor(s, o, 64);
        float inv = 1.0f / s;
        Pb[r][lane]       = f2bf(x0 * inv);
        Pb[r][lane + 64]  = f2bf(x1 * inv);
        Pb[r][lane + 128] = f2bf(x2 * inv);
        Pb[r][lane + 192] = f2bf(x3 * inv);
    }
    __syncthreads();

    // PV: wave w -> N-tile ct=w (cols w*16..w*16+15 within head h)
    int cl = lane & 15, kg = lane >> 4;
    f32x4 acc = {0.f, 0.f, 0.f, 0.f};
    const unsigned short* vb = Vbf + (size_t)b * SS * DD + h * 64 + w * 16 + cl;
#pragma unroll
    for (int s = 0; s < 8; ++s) {
        bf16x8 af = *(const bf16x8*)&Pb[cl][s * 32 + kg * 8];
        bf16x8 bfr;
#pragma unroll
        for (int e = 0; e < 8; ++e)
            bfr[e] = (short)vb[(size_t)(s * 32 + kg * 8 + e) * DD];
        acc = __builtin_amdgcn_mfma_f32_16x16x32_bf16(af, bfr, acc, 0, 0, 0);
    }

    int col = h * 64 + w * 16 + cl;
#pragma unroll
    for (int e = 0; e < 4; ++e) {
        size_t o = (size_t)(b * SS + i0 + kg * 4 + e) * DD + col;
        out[o] = fmaxf(token[o] + acc[e], 0.f);
    }
}

extern "C" void kernel_launch(void* const* d_in, const int* in_sizes, int n_in,
                              void* d_out, int out_size, void* d_ws, size_t ws_size,
                              hipStream_t stream) {
    const float* token = (const float*)d_in[0];
    const float* edge  = (const float*)d_in[1];
    const int*   mask  = (const int*)d_in[2];
    const float* W_v   = (const float*)d_in[3];
    const float* W_e   = (const float*)d_in[4];
    const float* w_rel = (const float*)d_in[5];
    float* out = (float*)d_out;

    char* ws = (char*)d_ws;
    unsigned short* upk = (unsigned short*)(ws);              // 8 KB
    unsigned short* wpk = (unsigned short*)(ws + 8192);       // 2.36 MB
    unsigned short* Vbf = (unsigned short*)(ws + 8192 + 2359296);  // 1.57 MB
    float* scores = (float*)(ws + 8192 + 2359296 + 1572864 + 1024);

    hipLaunchKernelGGL(k_prep, dim3(289),       dim3(256), 0, stream, W_e, w_rel, W_v, upk, wpk);
    hipLaunchKernelGGL(k_v,    dim3(32, 24),    dim3(256), 0, stream, token, wpk, Vbf);
    hipLaunchKernelGGL(k_sc,   dim3(SS * 4, BB), dim3(256), 0, stream, edge, mask, upk, scores);
    hipLaunchKernelGGL(k_ctx,  dim3(16, HH, BB), dim3(256), 0, stream, scores, Vbf, token, out);
}

// Round 15
// 54.978 us; speedup vs baseline: 2.5798x; 1.0577x over previous
//
#include <hip/hip_runtime.h>
#include <math.h>

#define BB 4
#define SS 256
#define DD 768
#define DEPC 100
#define HH 12

typedef short bf16x8 __attribute__((ext_vector_type(8)));
typedef float f32x4 __attribute__((ext_vector_type(4)));

#define GLDS(gp, lp)                                                        \
    __builtin_amdgcn_global_load_lds(                                       \
        (const __attribute__((address_space(1))) void*)(gp),                \
        (__attribute__((address_space(3))) void*)(lp), 16, 0, 0)

__device__ __forceinline__ unsigned short f2bf(float x) {
    unsigned int u = __float_as_uint(x);
    u += 0x7FFF + ((u >> 16) & 1);
    return (unsigned short)(u >> 16);
}
__device__ __forceinline__ float bf2f(unsigned short h) {
    return __uint_as_float(((unsigned int)h) << 16);
}

// ---------- K_prep: block 0 = u compute+pack; blocks 1..288 = W_v pack ----------
__global__ __launch_bounds__(256) void k_prep(const float* __restrict__ W_e,
                                              const float* __restrict__ w_rel,
                                              const float* __restrict__ W_v,
                                              unsigned short* __restrict__ upk,
                                              unsigned short* __restrict__ wpk) {
    int t = threadIdx.x;
    if (blockIdx.x == 0) {
        __shared__ float u_l[HH][DEPC];
        const float4* wr = (const float4*)w_rel;
        float4 wrv[16];
#pragma unroll
        for (int c = 0; c < 16; ++c) wrv[c] = wr[c];
        for (int e = t; e < DEPC * HH; e += 256) {
            int p = e / HH, h = e % HH;
            const float4* we = (const float4*)(W_e + p * DD + h * 64);
            float acc = 0.f;
#pragma unroll
            for (int c = 0; c < 16; ++c) {
                float4 a = we[c], b = wrv[c];
                acc += a.x * b.x + a.y * b.y + a.z * b.z + a.w * b.w;
            }
            u_l[h][p] = acc;
        }
        __syncthreads();
        int s = t >> 6, l = t & 63;
        int h = l & 15, kg = l >> 4;
        unsigned short hi[8], lo[8];
#pragma unroll
        for (int e = 0; e < 8; ++e) {
            int k = 32 * s + kg * 8 + e;
            float v = (h < HH && k < DEPC) ? u_l[h][k] : 0.f;
            unsigned short hb = f2bf(v);
            hi[e] = hb;
            lo[e] = f2bf(v - bf2f(hb));
        }
        unsigned short* dh = upk + (s * 64 + l) * 8;
        unsigned short* dl = upk + 2048 + (s * 64 + l) * 8;
#pragma unroll
        for (int e = 0; e < 8; ++e) { dh[e] = hi[e]; dl[e] = lo[e]; }
    } else {
        int unit = (blockIdx.x - 1) * 4 + (t >> 6);
        int lane = t & 63;
        int s = unit / 48, ct = unit % 48;
        int cl = lane & 15, kg = lane >> 4;
        unsigned short hi[8], lo[8];
#pragma unroll
        for (int e = 0; e < 8; ++e) {
            int k = s * 32 + kg * 8 + e;
            float v = W_v[(size_t)k * DD + ct * 16 + cl];
            unsigned short hb = f2bf(v);
            hi[e] = hb;
            lo[e] = f2bf(v - bf2f(hb));
        }
        size_t base = ((size_t)(s * 48 + ct) * 64 + lane) * 8;
        unsigned short* dh = wpk + base;
        unsigned short* dl = wpk + 589824 + base;
#pragma unroll
        for (int e = 0; e < 8; ++e) { dh[e] = hi[e]; dl[e] = lo[e]; }
    }
}

// ---------- device body: V = token @ W_v via MFMA (split-bf16) -> bf16 ----------
__device__ __forceinline__ void body_v(char* smem, int unit, int t,
                                       const float* __restrict__ A,
                                       const unsigned short* __restrict__ wpk,
                                       unsigned short* __restrict__ Vbf) {
    // smem layout: Ah [2][32][40] shorts, then Al [2][32][40]
    unsigned short* Ah = (unsigned short*)smem;
    unsigned short* Al = Ah + 2560;
#define AH(bf, r, c) Ah[((bf) * 32 + (r)) * 40 + (c)]
#define AL(bf, r, c) Al[((bf) * 32 + (r)) * 40 + (c)]
    int lane = t & 63, w = t >> 6;
    int wr = w >> 1, wc = w & 1;
    int vr = unit & 31, c0y = unit >> 5;   // 32 x 24
    int r0 = vr * 32;
    int srow = t >> 3, sq = t & 7;

    {
        float4 av = *(const float4*)&A[(size_t)(r0 + srow) * DD + 4 * sq];
        const float* af = (const float*)&av;
#pragma unroll
        for (int e = 0; e < 4; ++e) {
            unsigned short hb = f2bf(af[e]);
            AH(0, srow, 4 * sq + e) = hb;
            AL(0, srow, 4 * sq + e) = f2bf(af[e] - bf2f(hb));
        }
    }
    __syncthreads();

    int ct = c0y * 2 + wc;
    int fr = wr * 16 + (lane & 15);
    int kg = lane >> 4;
    f32x4 acc = {0.f, 0.f, 0.f, 0.f};

    for (int s = 0; s < 24; ++s) {
        float4 nx = {0, 0, 0, 0};
        if (s + 1 < 24)
            nx = *(const float4*)&A[(size_t)(r0 + srow) * DD + (s + 1) * 32 + 4 * sq];

        const unsigned short* bp = wpk + ((size_t)(s * 48 + ct) * 64 + lane) * 8;
        bf16x8 bh = *(const bf16x8*)bp;
        bf16x8 bl = *(const bf16x8*)(bp + 589824);
        bf16x8 ah = *(const bf16x8*)&AH(s & 1, fr, kg * 8);
        bf16x8 al = *(const bf16x8*)&AL(s & 1, fr, kg * 8);
        acc = __builtin_amdgcn_mfma_f32_16x16x32_bf16(ah, bh, acc, 0, 0, 0);
        acc = __builtin_amdgcn_mfma_f32_16x16x32_bf16(al, bh, acc, 0, 0, 0);
        acc = __builtin_amdgcn_mfma_f32_16x16x32_bf16(ah, bl, acc, 0, 0, 0);

        if (s + 1 < 24) {
            const float* nf = (const float*)&nx;
            int nb = (s + 1) & 1;
#pragma unroll
            for (int e = 0; e < 4; ++e) {
                unsigned short hb = f2bf(nf[e]);
                AH(nb, srow, 4 * sq + e) = hb;
                AL(nb, srow, 4 * sq + e) = f2bf(nf[e] - bf2f(hb));
            }
        }
        __syncthreads();
    }

    int col = c0y * 32 + wc * 16 + (lane & 15);
    int rowb = r0 + wr * 16 + (lane >> 4) * 4;
#pragma unroll
    for (int e = 0; e < 4; ++e)
        Vbf[(size_t)(rowb + e) * DD + col] = f2bf(acc[e]);
#undef AH
#undef AL
}

// ---------- device body: scores via MFMA ----------
__device__ __forceinline__ void body_sc(char* smem, int jc, int i, int b, int t,
                                        const float* __restrict__ edge,
                                        const int* __restrict__ mask,
                                        const unsigned short* __restrict__ upk,
                                        float* __restrict__ scores) {
    float* buf = (float*)smem;  // [64*100 + 32]
    int lane = t & 63, w = t >> 6;

    const float* src = edge + (size_t)((b * SS + i) * SS + jc * 64) * DEPC;
    for (int call = w; call < 25; call += 4)
        GLDS(src + call * 256 + lane * 4, &buf[call * 256]);
    if (t < 32) buf[6400 + t] = 0.f;

    bf16x8 uh[4], ul[4];
#pragma unroll
    for (int s = 0; s < 4; ++s) {
        uh[s] = *(const bf16x8*)(upk + (s * 64 + lane) * 8);
        ul[s] = *(const bf16x8*)(upk + 2048 + (s * 64 + lane) * 8);
    }
    __syncthreads();

    int arow = lane & 15, kg = lane >> 4;
    const float* rbase = buf + (w * 16 + arow) * DEPC;
    f32x4 acc = {0.f, 0.f, 0.f, 0.f};
#pragma unroll
    for (int s = 0; s < 4; ++s) {
        const float4* p = (const float4*)(rbase + 32 * s + kg * 8);
        float4 va = p[0], vb = p[1];
        float ev[8] = {va.x, va.y, va.z, va.w, vb.x, vb.y, vb.z, vb.w};
        bf16x8 ehi, elo;
#pragma unroll
        for (int e = 0; e < 8; ++e) {
            unsigned short hb = f2bf(ev[e]);
            ehi[e] = (short)hb;
            elo[e] = (short)f2bf(ev[e] - bf2f(hb));
        }
        acc = __builtin_amdgcn_mfma_f32_16x16x32_bf16(ehi, uh[s], acc, 0, 0, 0);
        acc = __builtin_amdgcn_mfma_f32_16x16x32_bf16(ehi, ul[s], acc, 0, 0, 0);
        acc = __builtin_amdgcn_mfma_f32_16x16x32_bf16(elo, uh[s], acc, 0, 0, 0);
    }

    int h = lane & 15;
    int j0 = jc * 64 + w * 16 + (lane >> 4) * 4;
    int4 mk = *(const int4*)(mask + (size_t)(b * SS + i) * SS + j0);
    float4 r;
    r.x = mk.x ? fmaxf(acc[0], 0.f) : -1e6f;
    r.y = mk.y ? fmaxf(acc[1], 0.f) : -1e6f;
    r.z = mk.z ? fmaxf(acc[2], 0.f) : -1e6f;
    r.w = mk.w ? fmaxf(acc[3], 0.f) : -1e6f;
    if (h < HH)
        *(float4*)&scores[(((size_t)b * HH + h) * SS + i) * SS + j0] = r;
}

// ---------- K_main: fused dispatch — k_v blocks (x<192) + k_sc blocks ----------
__global__ __launch_bounds__(256) void k_main(const float* __restrict__ token,
                                              const unsigned short* __restrict__ wpk,
                                              unsigned short* __restrict__ Vbf,
                                              const float* __restrict__ edge,
                                              const int* __restrict__ mask,
                                              const unsigned short* __restrict__ upk,
                                              float* __restrict__ scores) {
    __shared__ __align__(16) char smem[25728];
    int t = threadIdx.x;
    int x = blockIdx.x, b = blockIdx.y;
    if (x < 192) {
        int unit = b * 192 + x;  // [0, 768)
        body_v(smem, unit, t, token, wpk, Vbf);
    } else {
        int xx = x - 192;
        body_sc(smem, xx & 3, xx >> 2, b, t, edge, mask, upk, scores);
    }
}

// ---------- K4: softmax + PV via MFMA.  Block = (i-tile16, h, b) ----------
__global__ __launch_bounds__(256) void k_ctx(const float* __restrict__ scores,
                                             const unsigned short* __restrict__ Vbf,
                                             const float* __restrict__ token,
                                             float* __restrict__ out) {
    __shared__ float P[16][260];
    __shared__ unsigned short Pb[16][264];
    int t = threadIdx.x;
    int i0 = blockIdx.x * 16, h = blockIdx.y, b = blockIdx.z;
    int lane = t & 63, w = t >> 6;

    const float* sbase = scores + (((size_t)b * HH + h) * SS + i0) * SS;
#pragma unroll
    for (int k = 0; k < 4; ++k) {
        int idx = t + 256 * k;
        int r = idx >> 6, jc = idx & 63;
        float4 v = *(const float4*)(sbase + (size_t)r * SS + 4 * jc);
        *(float4*)&P[r][4 * jc] = v;
    }
    __syncthreads();

    for (int r = w; r < 16; r += 4) {
        float x0 = P[r][lane],       x1 = P[r][lane + 64];
        float x2 = P[r][lane + 128], x3 = P[r][lane + 192];
        float m = fmaxf(fmaxf(x0, x1), fmaxf(x2, x3));
#pragma unroll
        for (int o = 32; o > 0; o >>= 1) m = fmaxf(m, __shfl_xor(m, o, 64));
        x0 = __expf(x0 - m); x1 = __expf(x1 - m);
        x2 = __expf(x2 - m); x3 = __expf(x3 - m);
        float s = x0 + x1 + x2 + x3;
#pragma unroll
        for (int o = 32; o > 0; o >>= 1) s += __shfl_xor(s, o, 64);
        float inv = 1.0f / s;
        Pb[r][lane]       = f2bf(x0 * inv);
        Pb[r][lane + 64]  = f2bf(x1 * inv);
        Pb[r][lane + 128] = f2bf(x2 * inv);
        Pb[r][lane + 192] = f2bf(x3 * inv);
    }
    __syncthreads();

    int cl = lane & 15, kg = lane >> 4;
    f32x4 acc = {0.f, 0.f, 0.f, 0.f};
    const unsigned short* vb = Vbf + (size_t)b * SS * DD + h * 64 + w * 16 + cl;
#pragma unroll
    for (int s = 0; s < 8; ++s) {
        bf16x8 af = *(const bf16x8*)&Pb[cl][s * 32 + kg * 8];
        bf16x8 bfr;
#pragma unroll
        for (int e = 0; e < 8; ++e)
            bfr[e] = (short)vb[(size_t)(s * 32 + kg * 8 + e) * DD];
        acc = __builtin_amdgcn_mfma_f32_16x16x32_bf16(af, bfr, acc, 0, 0, 0);
    }

    int col = h * 64 + w * 16 + cl;
#pragma unroll
    for (int e = 0; e < 4; ++e) {
        size_t o = (size_t)(b * SS + i0 + kg * 4 + e) * DD + col;
        out[o] = fmaxf(token[o] + acc[e], 0.f);
    }
}

extern "C" void kernel_launch(void* const* d_in, const int* in_sizes, int n_in,
                              void* d_out, int out_size, void* d_ws, size_t ws_size,
                              hipStream_t stream) {
    const float* token = (const float*)d_in[0];
    const float* edge  = (const float*)d_in[1];
    const int*   mask  = (const int*)d_in[2];
    const float* W_v   = (const float*)d_in[3];
    const float* W_e   = (const float*)d_in[4];
    const float* w_rel = (const float*)d_in[5];
    float* out = (float*)d_out;

    char* ws = (char*)d_ws;
    unsigned short* upk = (unsigned short*)(ws);              // 8 KB
    unsigned short* wpk = (unsigned short*)(ws + 8192);       // 2.36 MB
    unsigned short* Vbf = (unsigned short*)(ws + 8192 + 2359296);  // 1.57 MB
    float* scores = (float*)(ws + 8192 + 2359296 + 1572864 + 1024);

    hipLaunchKernelGGL(k_prep, dim3(289),             dim3(256), 0, stream, W_e, w_rel, W_v, upk, wpk);
    hipLaunchKernelGGL(k_main, dim3(192 + SS * 4, BB), dim3(256), 0, stream,
                       token, wpk, Vbf, edge, mask, upk, scores);
    hipLaunchKernelGGL(k_ctx,  dim3(16, HH, BB),      dim3(256), 0, stream, scores, Vbf, token, out);
}

// Round 16
// 54.136 us; speedup vs baseline: 2.6200x; 1.0156x over previous
//
#include <hip/hip_runtime.h>
#include <math.h>

#define BB 4
#define SS 256
#define DD 768
#define DEPC 100
#define HH 12

typedef short bf16x8 __attribute__((ext_vector_type(8)));
typedef float f32x4 __attribute__((ext_vector_type(4)));

#define GLDS(gp, lp)                                                        \
    __builtin_amdgcn_global_load_lds(                                       \
        (const __attribute__((address_space(1))) void*)(gp),                \
        (__attribute__((address_space(3))) void*)(lp), 16, 0, 0)

__device__ __forceinline__ unsigned short f2bf(float x) {
    unsigned int u = __float_as_uint(x);
    u += 0x7FFF + ((u >> 16) & 1);
    return (unsigned short)(u >> 16);
}
__device__ __forceinline__ float bf2f(unsigned short h) {
    return __uint_as_float(((unsigned int)h) << 16);
}

// ---------- K_prep: block 0 = u compute+pack; blocks 1..288 = W_v pack ----------
__global__ __launch_bounds__(256) void k_prep(const float* __restrict__ W_e,
                                              const float* __restrict__ w_rel,
                                              const float* __restrict__ W_v,
                                              unsigned short* __restrict__ upk,
                                              unsigned short* __restrict__ wpk) {
    int t = threadIdx.x;
    if (blockIdx.x == 0) {
        __shared__ float u_l[HH][DEPC];
        const float4* wr = (const float4*)w_rel;
        float4 wrv[16];
#pragma unroll
        for (int c = 0; c < 16; ++c) wrv[c] = wr[c];
        for (int e = t; e < DEPC * HH; e += 256) {
            int p = e / HH, h = e % HH;
            const float4* we = (const float4*)(W_e + p * DD + h * 64);
            float acc = 0.f;
#pragma unroll
            for (int c = 0; c < 16; ++c) {
                float4 a = we[c], b = wrv[c];
                acc += a.x * b.x + a.y * b.y + a.z * b.z + a.w * b.w;
            }
            u_l[h][p] = acc;
        }
        __syncthreads();
        int s = t >> 6, l = t & 63;
        int h = l & 15, kg = l >> 4;
        unsigned short hi[8], lo[8];
#pragma unroll
        for (int e = 0; e < 8; ++e) {
            int k = 32 * s + kg * 8 + e;
            float v = (h < HH && k < DEPC) ? u_l[h][k] : 0.f;
            unsigned short hb = f2bf(v);
            hi[e] = hb;
            lo[e] = f2bf(v - bf2f(hb));
        }
        unsigned short* dh = upk + (s * 64 + l) * 8;
        unsigned short* dl = upk + 2048 + (s * 64 + l) * 8;
#pragma unroll
        for (int e = 0; e < 8; ++e) { dh[e] = hi[e]; dl[e] = lo[e]; }
    } else {
        int unit = (blockIdx.x - 1) * 4 + (t >> 6);
        int lane = t & 63;
        int s = unit / 48, ct = unit % 48;
        int cl = lane & 15, kg = lane >> 4;
        unsigned short hi[8], lo[8];
#pragma unroll
        for (int e = 0; e < 8; ++e) {
            int k = s * 32 + kg * 8 + e;
            float v = W_v[(size_t)k * DD + ct * 16 + cl];
            unsigned short hb = f2bf(v);
            hi[e] = hb;
            lo[e] = f2bf(v - bf2f(hb));
        }
        size_t base = ((size_t)(s * 48 + ct) * 64 + lane) * 8;
        unsigned short* dh = wpk + base;
        unsigned short* dl = wpk + 589824 + base;
#pragma unroll
        for (int e = 0; e < 8; ++e) { dh[e] = hi[e]; dl[e] = lo[e]; }
    }
}

// ---------- device body: V = token @ W_v via MFMA (split-bf16) -> bf16 ----------
__device__ __forceinline__ void body_v(char* smem, int unit, int t,
                                       const float* __restrict__ A,
                                       const unsigned short* __restrict__ wpk,
                                       unsigned short* __restrict__ Vbf) {
    unsigned short* Ah = (unsigned short*)smem;
    unsigned short* Al = Ah + 2560;
#define AH(bf, r, c) Ah[((bf) * 32 + (r)) * 40 + (c)]
#define AL(bf, r, c) Al[((bf) * 32 + (r)) * 40 + (c)]
    int lane = t & 63, w = t >> 6;
    int wr = w >> 1, wc = w & 1;
    int vr = unit & 31, c0y = unit >> 5;
    int r0 = vr * 32;
    int srow = t >> 3, sq = t & 7;

    {
        float4 av = *(const float4*)&A[(size_t)(r0 + srow) * DD + 4 * sq];
        const float* af = (const float*)&av;
#pragma unroll
        for (int e = 0; e < 4; ++e) {
            unsigned short hb = f2bf(af[e]);
            AH(0, srow, 4 * sq + e) = hb;
            AL(0, srow, 4 * sq + e) = f2bf(af[e] - bf2f(hb));
        }
    }
    __syncthreads();

    int ct = c0y * 2 + wc;
    int fr = wr * 16 + (lane & 15);
    int kg = lane >> 4;
    f32x4 acc = {0.f, 0.f, 0.f, 0.f};

    for (int s = 0; s < 24; ++s) {
        float4 nx = {0, 0, 0, 0};
        if (s + 1 < 24)
            nx = *(const float4*)&A[(size_t)(r0 + srow) * DD + (s + 1) * 32 + 4 * sq];

        const unsigned short* bp = wpk + ((size_t)(s * 48 + ct) * 64 + lane) * 8;
        bf16x8 bh = *(const bf16x8*)bp;
        bf16x8 bl = *(const bf16x8*)(bp + 589824);
        bf16x8 ah = *(const bf16x8*)&AH(s & 1, fr, kg * 8);
        bf16x8 al = *(const bf16x8*)&AL(s & 1, fr, kg * 8);
        acc = __builtin_amdgcn_mfma_f32_16x16x32_bf16(ah, bh, acc, 0, 0, 0);
        acc = __builtin_amdgcn_mfma_f32_16x16x32_bf16(al, bh, acc, 0, 0, 0);
        acc = __builtin_amdgcn_mfma_f32_16x16x32_bf16(ah, bl, acc, 0, 0, 0);

        if (s + 1 < 24) {
            const float* nf = (const float*)&nx;
            int nb = (s + 1) & 1;
#pragma unroll
            for (int e = 0; e < 4; ++e) {
                unsigned short hb = f2bf(nf[e]);
                AH(nb, srow, 4 * sq + e) = hb;
                AL(nb, srow, 4 * sq + e) = f2bf(nf[e] - bf2f(hb));
            }
        }
        __syncthreads();
    }

    int col = c0y * 32 + wc * 16 + (lane & 15);
    int rowb = r0 + wr * 16 + (lane >> 4) * 4;
#pragma unroll
    for (int e = 0; e < 4; ++e)
        Vbf[(size_t)(rowb + e) * DD + col] = f2bf(acc[e]);
#undef AH
#undef AL
}

// ---------- device body: scores via MFMA — INDEPENDENT WAVES, zero barriers ----------
// Wave stages its own 16 j-rows (6.4 KB) into a private slice, waits wave-local
// vmcnt(0), computes its own 16x12 MFMA tile. No cross-wave coupling.
__device__ __forceinline__ void body_sc(char* smem, int jc, int i, int b, int t,
                                        const float* __restrict__ edge,
                                        const int* __restrict__ mask,
                                        const unsigned short* __restrict__ upk,
                                        float* __restrict__ scores) {
    int lane = t & 63, w = t >> 6;
    float* buf = (float*)smem + w * 1632;  // 16*100 data + pad (row15 reads to 1627)

    // wave's 16 rows = 1600 floats = 400 float4; 7 calls (last partial)
    const float* src = edge + (size_t)((b * SS + i) * SS + jc * 64 + w * 16) * DEPC;
#pragma unroll
    for (int call = 0; call < 7; ++call) {
        int idx = call * 64 + lane;
        if (idx < 400) GLDS(src + idx * 4, buf + call * 256);
    }
    if (lane < 28) buf[1600 + lane] = 0.f;  // k-pad: garbage*0 must stay finite

    bf16x8 uh[4], ul[4];
#pragma unroll
    for (int s = 0; s < 4; ++s) {
        uh[s] = *(const bf16x8*)(upk + (s * 64 + lane) * 8);
        ul[s] = *(const bf16x8*)(upk + 2048 + (s * 64 + lane) * 8);
    }

    int arow = lane & 15, kg = lane >> 4;
    int j0 = jc * 64 + w * 16 + kg * 4;
    int4 mk = *(const int4*)(mask + (size_t)(b * SS + i) * SS + j0);

    asm volatile("s_waitcnt vmcnt(0)" ::: "memory");  // wave-local: own stages done
    __builtin_amdgcn_sched_barrier(0);

    const float* rbase = buf + arow * DEPC;
    f32x4 acc = {0.f, 0.f, 0.f, 0.f};
#pragma unroll
    for (int s = 0; s < 4; ++s) {
        const float4* p = (const float4*)(rbase + 32 * s + kg * 8);
        float4 va = p[0], vb = p[1];
        float ev[8] = {va.x, va.y, va.z, va.w, vb.x, vb.y, vb.z, vb.w};
        bf16x8 ehi, elo;
#pragma unroll
        for (int e = 0; e < 8; ++e) {
            unsigned short hb = f2bf(ev[e]);
            ehi[e] = (short)hb;
            elo[e] = (short)f2bf(ev[e] - bf2f(hb));
        }
        acc = __builtin_amdgcn_mfma_f32_16x16x32_bf16(ehi, uh[s], acc, 0, 0, 0);
        acc = __builtin_amdgcn_mfma_f32_16x16x32_bf16(ehi, ul[s], acc, 0, 0, 0);
        acc = __builtin_amdgcn_mfma_f32_16x16x32_bf16(elo, uh[s], acc, 0, 0, 0);
    }

    int h = lane & 15;
    float4 r;
    r.x = mk.x ? fmaxf(acc[0], 0.f) : -1e6f;
    r.y = mk.y ? fmaxf(acc[1], 0.f) : -1e6f;
    r.z = mk.z ? fmaxf(acc[2], 0.f) : -1e6f;
    r.w = mk.w ? fmaxf(acc[3], 0.f) : -1e6f;
    if (h < HH)
        *(float4*)&scores[(((size_t)b * HH + h) * SS + i) * SS + j0] = r;
}

// ---------- K_main: fused dispatch — k_v blocks (x<192) + k_sc blocks ----------
__global__ __launch_bounds__(256) void k_main(const float* __restrict__ token,
                                              const unsigned short* __restrict__ wpk,
                                              unsigned short* __restrict__ Vbf,
                                              const float* __restrict__ edge,
                                              const int* __restrict__ mask,
                                              const unsigned short* __restrict__ upk,
                                              float* __restrict__ scores) {
    __shared__ __align__(16) char smem[26112];
    int t = threadIdx.x;
    int x = blockIdx.x, b = blockIdx.y;
    if (x < 192) {
        int unit = b * 192 + x;
        body_v(smem, unit, t, token, wpk, Vbf);
    } else {
        int xx = x - 192;
        body_sc(smem, xx & 3, xx >> 2, b, t, edge, mask, upk, scores);
    }
}

// ---------- K4: softmax + PV via MFMA.  Block = (i-tile16, h, b) ----------
__global__ __launch_bounds__(256) void k_ctx(const float* __restrict__ scores,
                                             const unsigned short* __restrict__ Vbf,
                                             const float* __restrict__ token,
                                             float* __restrict__ out) {
    __shared__ float P[16][260];
    __shared__ unsigned short Pb[16][264];
    int t = threadIdx.x;
    int i0 = blockIdx.x * 16, h = blockIdx.y, b = blockIdx.z;
    int lane = t & 63, w = t >> 6;

    const float* sbase = scores + (((size_t)b * HH + h) * SS + i0) * SS;
#pragma unroll
    for (int k = 0; k < 4; ++k) {
        int idx = t + 256 * k;
        int r = idx >> 6, jc = idx & 63;
        float4 v = *(const float4*)(sbase + (size_t)r * SS + 4 * jc);
        *(float4*)&P[r][4 * jc] = v;
    }
    __syncthreads();

    for (int r = w; r < 16; r += 4) {
        float x0 = P[r][lane],       x1 = P[r][lane + 64];
        float x2 = P[r][lane + 128], x3 = P[r][lane + 192];
        float m = fmaxf(fmaxf(x0, x1), fmaxf(x2, x3));
#pragma unroll
        for (int o = 32; o > 0; o >>= 1) m = fmaxf(m, __shfl_xor(m, o, 64));
        x0 = __expf(x0 - m); x1 = __expf(x1 - m);
        x2 = __expf(x2 - m); x3 = __expf(x3 - m);
        float s = x0 + x1 + x2 + x3;
#pragma unroll
        for (int o = 32; o > 0; o >>= 1) s += __shfl_xor(s, o, 64);
        float inv = 1.0f / s;
        Pb[r][lane]       = f2bf(x0 * inv);
        Pb[r][lane + 64]  = f2bf(x1 * inv);
        Pb[r][lane + 128] = f2bf(x2 * inv);
        Pb[r][lane + 192] = f2bf(x3 * inv);
    }
    __syncthreads();

    int cl = lane & 15, kg = lane >> 4;
    f32x4 acc = {0.f, 0.f, 0.f, 0.f};
    const unsigned short* vb = Vbf + (size_t)b * SS * DD + h * 64 + w * 16 + cl;
#pragma unroll
    for (int s = 0; s < 8; ++s) {
        bf16x8 af = *(const bf16x8*)&Pb[cl][s * 32 + kg * 8];
        bf16x8 bfr;
#pragma unroll
        for (int e = 0; e < 8; ++e)
            bfr[e] = (short)vb[(size_t)(s * 32 + kg * 8 + e) * DD];
        acc = __builtin_amdgcn_mfma_f32_16x16x32_bf16(af, bfr, acc, 0, 0, 0);
    }

    int col = h * 64 + w * 16 + cl;
#pragma unroll
    for (int e = 0; e < 4; ++e) {
        size_t o = (size_t)(b * SS + i0 + kg * 4 + e) * DD + col;
        out[o] = fmaxf(token[o] + acc[e], 0.f);
    }
}

extern "C" void kernel_launch(void* const* d_in, const int* in_sizes, int n_in,
                              void* d_out, int out_size, void* d_ws, size_t ws_size,
                              hipStream_t stream) {
    const float* token = (const float*)d_in[0];
    const float* edge  = (const float*)d_in[1];
    const int*   mask  = (const int*)d_in[2];
    const float* W_v   = (const float*)d_in[3];
    const float* W_e   = (const float*)d_in[4];
    const float* w_rel = (const float*)d_in[5];
    float* out = (float*)d_out;

    char* ws = (char*)d_ws;
    unsigned short* upk = (unsigned short*)(ws);              // 8 KB
    unsigned short* wpk = (unsigned short*)(ws + 8192);       // 2.36 MB
    unsigned short* Vbf = (unsigned short*)(ws + 8192 + 2359296);  // 1.57 MB
    float* scores = (float*)(ws + 8192 + 2359296 + 1572864 + 1024);

    hipLaunchKernelGGL(k_prep, dim3(289),              dim3(256), 0, stream, W_e, w_rel, W_v, upk, wpk);
    hipLaunchKernelGGL(k_main, dim3(192 + SS * 4, BB), dim3(256), 0, stream,
                       token, wpk, Vbf, edge, mask, upk, scores);
    hipLaunchKernelGGL(k_ctx,  dim3(16, HH, BB),       dim3(256), 0, stream, scores, Vbf, token, out);
}